// Round 2
// baseline (355.741 us; speedup 1.0000x reference)
//
#include <hip/hip_runtime.h>

typedef __bf16 bf16_t;
typedef __attribute__((ext_vector_type(8))) __bf16 bf16x8;
typedef __attribute__((ext_vector_type(4))) __bf16 bf16x4;
typedef __attribute__((ext_vector_type(4))) float f32x4;

constexpr int Bc = 4, Sc = 2048, Dc = 512, Hc = 4, HDc = 128;
constexpr int Mrows = Bc * Sc;  // 8192

__device__ inline void gl2lds(const void* g, void* l) {
  __builtin_amdgcn_global_load_lds(
      (__attribute__((address_space(1))) void*)g,
      (__attribute__((address_space(3))) void*)l, 16, 0, 0);
}

// ---------- weight transpose + cast: dst[n*K+k] = bf16(src[k*N+n]) ----------
__global__ __launch_bounds__(256) void wt_transpose_k(const float* __restrict__ src,
                                                      bf16_t* __restrict__ dst,
                                                      int K, int N) {
  __shared__ float tile[32][33];
  const int tx = threadIdx.x & 31, ty = threadIdx.x >> 5;
  const int n0 = blockIdx.x * 32, k0 = blockIdx.y * 32;
#pragma unroll
  for (int i = 0; i < 4; i++)
    tile[ty + i * 8][tx] = src[(long)(k0 + ty + i * 8) * N + n0 + tx];
  __syncthreads();
#pragma unroll
  for (int i = 0; i < 4; i++)
    dst[(long)(n0 + ty + i * 8) * K + k0 + tx] = (bf16_t)tile[tx][ty + i * 8];
}

// ---------- fp32 -> bf16 cast (8 elements/thread) ----------
__global__ __launch_bounds__(256) void cvt_k(const float* __restrict__ x,
                                             bf16_t* __restrict__ y) {
  const long i = ((long)blockIdx.x * 256 + threadIdx.x) * 8;
  const float4 a = *(const float4*)(x + i);
  const float4 c = *(const float4*)(x + i + 4);
  bf16x8 o;
  o[0] = (bf16_t)a.x; o[1] = (bf16_t)a.y; o[2] = (bf16_t)a.z; o[3] = (bf16_t)a.w;
  o[4] = (bf16_t)c.x; o[5] = (bf16_t)c.y; o[6] = (bf16_t)c.z; o[7] = (bf16_t)c.w;
  *(bf16x8*)(y + i) = o;
}

// ---------- m97-style 128x128 MFMA GEMM, A bf16 [M][K], Bt bf16 [N][K] ----------
// OMODE: 0 = relu+bias -> bf16 ; 1 = bias -> bf16 ; 2 = qkv scatter bf16
template <int OMODE>
__global__ __launch_bounds__(256, 2) void gemm128_k(
    const bf16_t* __restrict__ A, const bf16_t* __restrict__ Bt,
    const float* __restrict__ bias0, const float* __restrict__ bias1,
    const float* __restrict__ bias2, void* __restrict__ out0,
    void* __restrict__ out1, void* __restrict__ out2, int N, int K) {
  __shared__ bf16_t As[128 * 32];  // row-major [128][32], unpadded (global_load_lds)
  __shared__ bf16_t Bs[128 * 32];
  const int t = threadIdx.x;
  const int n0 = blockIdx.x * 128, m0 = blockIdx.y * 128;
  const int lane = t & 63, wave = t >> 6;
  const int quad = lane >> 4, ln = lane & 15;
  const int wm = wave >> 1, wn = wave & 1;  // 2x2 waves, 64x64 each
  const int srow = wave * 16 + (lane >> 2);
  const int scol = (lane & 3) * 8;
  const bf16_t* aseg = A + (long)(m0 + srow) * K + scol;
  const bf16_t* bseg = Bt + (long)(n0 + srow) * K + scol;
  bf16_t* asl = &As[(wave * 16) * 32];  // wave-uniform LDS base
  bf16_t* bsl = &Bs[(wave * 16) * 32];
  f32x4 acc[4][4] = {};
  for (int k0 = 0; k0 < K; k0 += 32) {
#pragma unroll
    for (int i = 0; i < 2; i++) {
      gl2lds(aseg + (long)i * 64 * K + k0, asl + i * 64 * 32);
      gl2lds(bseg + (long)i * 64 * K + k0, bsl + i * 64 * 32);
    }
    __syncthreads();
    bf16x8 af[4], bfr[4];
#pragma unroll
    for (int mt = 0; mt < 4; mt++)
      af[mt] = *(const bf16x8*)&As[(wm * 64 + mt * 16 + ln) * 32 + quad * 8];
#pragma unroll
    for (int nt = 0; nt < 4; nt++)
      bfr[nt] = *(const bf16x8*)&Bs[(wn * 64 + nt * 16 + ln) * 32 + quad * 8];
#pragma unroll
    for (int mt = 0; mt < 4; mt++)
#pragma unroll
      for (int nt = 0; nt < 4; nt++)
        acc[mt][nt] = __builtin_amdgcn_mfma_f32_16x16x32_bf16(af[mt], bfr[nt],
                                                              acc[mt][nt], 0, 0, 0);
    __syncthreads();
  }
#pragma unroll
  for (int nt = 0; nt < 4; nt++) {
    const int gcol = n0 + wn * 64 + nt * 16 + ln;
    if constexpr (OMODE == 0 || OMODE == 1) {
      const float bv = bias0[gcol];
      bf16_t* o = (bf16_t*)out0;
#pragma unroll
      for (int mt = 0; mt < 4; mt++)
#pragma unroll
        for (int r = 0; r < 4; r++) {
          const int grow = m0 + wm * 64 + mt * 16 + quad * 4 + r;
          float vv = acc[mt][nt][r] + bv;
          if constexpr (OMODE == 0) vv = vv > 0.f ? vv : 0.f;
          o[(long)grow * N + gcol] = (bf16_t)vv;
        }
    } else {
      const int which = gcol >> 9, n = gcol & 511;
      const int hh = n >> 7, hd = n & 127;
      const float bv = (which == 0 ? bias0 : which == 1 ? bias1 : bias2)[n];
      bf16_t* o = (bf16_t*)(which == 0 ? out0 : which == 1 ? out1 : out2);
#pragma unroll
      for (int mt = 0; mt < 4; mt++)
#pragma unroll
        for (int r = 0; r < 4; r++) {
          const int grow = m0 + wm * 64 + mt * 16 + quad * 4 + r;
          const int b = grow >> 11, s = grow & 2047;
          const float vv = acc[mt][nt][r] + bv;
          long idx;
          if (which == 2)  // v stored transposed [b,h,hd,s]
            idx = ((long)(b * Hc + hh) * HDc + hd) * Sc + s;
          else             // q,k stored [b,h,s,hd]
            idx = ((long)(b * Hc + hh) * Sc + s) * HDc + hd;
          o[idx] = (bf16_t)vv;
        }
    }
  }
}

// ---------- LayerNorm(xa_fp32 + xb_bf16): one wave per row of 512 ----------
template <int DUAL>
__global__ __launch_bounds__(256) void ln_k(const float* __restrict__ xa,
                                            const bf16_t* __restrict__ xb,
                                            const float* __restrict__ gamma,
                                            const float* __restrict__ beta,
                                            float* __restrict__ out,
                                            bf16_t* __restrict__ outb) {
  const int wave = threadIdx.x >> 6, lane = threadIdx.x & 63;
  const long row = (long)blockIdx.x * 4 + wave;
  const float* a = xa + row * Dc;
  const bf16_t* bp = xb + row * Dc;
  float vv[8];
  float s = 0.f, s2 = 0.f;
#pragma unroll
  for (int i = 0; i < 2; i++) {
    const float4 va = *(const float4*)(a + lane * 4 + i * 256);
    const bf16x4 vb = *(const bf16x4*)(bp + lane * 4 + i * 256);
    const float xs[4] = {va.x, va.y, va.z, va.w};
#pragma unroll
    for (int j = 0; j < 4; j++) {
      const float x = xs[j] + (float)vb[j];
      vv[i * 4 + j] = x;
      s += x;
      s2 += x * x;
    }
  }
#pragma unroll
  for (int off = 1; off < 64; off <<= 1) {
    s += __shfl_xor(s, off, 64);
    s2 += __shfl_xor(s2, off, 64);
  }
  const float mu = s * (1.f / Dc);
  const float var = s2 * (1.f / Dc) - mu * mu;
  const float rstd = rsqrtf(var + 1e-5f);
#pragma unroll
  for (int i = 0; i < 2; i++)
#pragma unroll
    for (int j = 0; j < 4; j++) {
      const int col = lane * 4 + i * 256 + j;
      const float o = (vv[i * 4 + j] - mu) * rstd * gamma[col] + beta[col];
      out[row * Dc + col] = o;
      if constexpr (DUAL) outb[row * Dc + col] = (bf16_t)o;
    }
}

// ---------- flash attention, un-normalized one-pass softmax ----------
// q,k: bf16 [b,h,s,hd]; v: bf16 [b,h,hd,s]; ctx out: bf16 [b,s,h*HD+hd]
__global__ __launch_bounds__(256, 2) void attn_k(const bf16_t* __restrict__ q,
                                                 const bf16_t* __restrict__ k,
                                                 const bf16_t* __restrict__ v,
                                                 const float* __restrict__ pos,
                                                 const float* __restrict__ alphap,
                                                 bf16_t* __restrict__ ctx) {
  __shared__ bf16_t Ks[64][136];   // [key][hd], padded (272 B rows, 16B-mult)
  __shared__ bf16_t Vts[128][64];  // [hd][key], XOR-swizzled 8-elem groups
  __shared__ bf16_t Ps[4][16][72]; // per-wave P: [qrow][key]
  __shared__ float pk[64][4];      // key positions x,y,z,pad
  const int t = threadIdx.x;
  const int qt = blockIdx.x, h = blockIdx.y, b = blockIdx.z;
  const int q0 = qt * 64;
  const int wave = t >> 6, lane = t & 63, quad = lane >> 4, ln = lane & 15;
  const float l2e = 1.4426950408889634f;
  const float scale_l2 = 0.08838834764831845f * l2e;  // (1/sqrt(128))*log2(e)
  const float alpha_l2 = alphap[0] * l2e;
  const bf16_t* qbase = q + ((long)(b * Hc + h) * Sc + q0) * HDc;
  const bf16_t* kbase = k + (long)(b * Hc + h) * Sc * HDc;
  const bf16_t* vbase = v + (long)(b * Hc + h) * HDc * Sc;

  // Q fragments + q-positions live in registers (no LDS, no staging barrier)
  bf16x8 qf[4];
#pragma unroll
  for (int kc = 0; kc < 4; kc++)
    qf[kc] = *(const bf16x8*)(qbase + (wave * 16 + ln) * HDc + kc * 32 + quad * 8);
  float pqx[4], pqy[4], pqz[4];
#pragma unroll
  for (int r = 0; r < 4; r++) {
    const long pr = ((long)b * Sc + q0 + wave * 16 + quad * 4 + r) * 3;
    pqx[r] = pos[pr]; pqy[r] = pos[pr + 1]; pqz[r] = pos[pr + 2];
  }

  // staging geometry (loop-invariant)
  const int krow = t >> 4, kcol = (t & 15) * 8;   // K: rows krow+16i
  const int vrow = t >> 3, vg = t & 7;            // V: rows vrow+32i
  const int vsw = vg ^ (vrow & 7);                // swizzled col-group
  uint4 kreg[4], vreg[4];
  float pkx = 0.f, pky = 0.f, pkz = 0.f;
  auto load_tile = [&](int kt) {
#pragma unroll
    for (int i = 0; i < 4; i++)
      kreg[i] = *(const uint4*)(kbase + (long)(kt * 64 + krow + 16 * i) * HDc + kcol);
#pragma unroll
    for (int i = 0; i < 4; i++)
      vreg[i] = *(const uint4*)(vbase + (long)(vrow + 32 * i) * Sc + kt * 64 + vg * 8);
    if (t < 64) {
      const long pr = ((long)b * Sc + kt * 64 + t) * 3;
      pkx = pos[pr]; pky = pos[pr + 1]; pkz = pos[pr + 2];
    }
  };
  load_tile(0);

  float rs[4] = {0.f, 0.f, 0.f, 0.f};
  f32x4 acc_o[8] = {};

  for (int kt = 0; kt < Sc / 64; kt++) {
    __syncthreads();  // previous iteration's LDS readers done
#pragma unroll
    for (int i = 0; i < 4; i++) *(uint4*)&Ks[krow + 16 * i][kcol] = kreg[i];
#pragma unroll
    for (int i = 0; i < 4; i++) *(uint4*)&Vts[vrow + 32 * i][vsw * 8] = vreg[i];
    if (t < 64) { pk[t][0] = pkx; pk[t][1] = pky; pk[t][2] = pkz; }
    __syncthreads();  // tile visible to all
    if (kt < Sc / 64 - 1) load_tile(kt + 1);  // prefetch overlaps compute below

    // S = Q @ K^T (16 q-rows x 64 keys per wave)
    f32x4 sacc[4] = {};
#pragma unroll
    for (int kc = 0; kc < 4; kc++)
#pragma unroll
      for (int ct = 0; ct < 4; ct++) {
        const bf16x8 bfv = *(const bf16x8*)&Ks[ct * 16 + ln][kc * 32 + quad * 8];
        sacc[ct] = __builtin_amdgcn_mfma_f32_16x16x32_bf16(qf[kc], bfv, sacc[ct], 0, 0, 0);
      }
    // un-normalized softmax: p = 2^(s*scale*l2e - alpha*l2e*d2); lane-local sum
#pragma unroll
    for (int ct = 0; ct < 4; ct++) {
      const int kk = ct * 16 + ln;
      const float4 pkv = *(const float4*)&pk[kk][0];
#pragma unroll
      for (int r = 0; r < 4; r++) {
        const float dx = pqx[r] - pkv.x, dy = pqy[r] - pkv.y, dz = pqz[r] - pkv.z;
        const float d2 = dx * dx + dy * dy + dz * dz;
        const float p = __builtin_amdgcn_exp2f(sacc[ct][r] * scale_l2 - alpha_l2 * d2);
        rs[r] += p;
        Ps[wave][quad * 4 + r][kk] = (bf16_t)p;  // wave-private: no barrier needed
      }
    }
    // O += P @ V
#pragma unroll
    for (int s2 = 0; s2 < 2; s2++) {
      const bf16x8 pf = *(const bf16x8*)&Ps[wave][ln][s2 * 32 + quad * 8];
#pragma unroll
      for (int nt = 0; nt < 8; nt++) {
        const bf16x8 vf =
            *(const bf16x8*)&Vts[nt * 16 + ln][((s2 * 4 + quad) ^ (ln & 7)) * 8];
        acc_o[nt] = __builtin_amdgcn_mfma_f32_16x16x32_bf16(pf, vf, acc_o[nt], 0, 0, 0);
      }
    }
  }

  // one final 16-lane reduction of the softmax denominator
#pragma unroll
  for (int off = 1; off < 16; off <<= 1)
#pragma unroll
    for (int r = 0; r < 4; r++) rs[r] += __shfl_xor(rs[r], off, 64);
  float rinv[4];
#pragma unroll
  for (int r = 0; r < 4; r++) rinv[r] = 1.f / rs[r];
#pragma unroll
  for (int nt = 0; nt < 8; nt++)
#pragma unroll
    for (int r = 0; r < 4; r++) {
      const int qrow = wave * 16 + quad * 4 + r;
      ctx[((long)b * Sc + q0 + qrow) * Dc + h * HDc + nt * 16 + ln] =
          (bf16_t)(acc_o[nt][r] * rinv[r]);
    }
}

// ---------------- workspace layout (bytes) ----------------
constexpr size_t SE_OFF = 0;                       // fp32 8192x512   (16 MB)
constexpr size_t SQB_OFF = 16777216;               // bf16 8192x512: squeeze out, later ctx
constexpr size_t SEB_OFF = 25165824;               // bf16 8192x512: se bf16 copy
constexpr size_t Q_OFF = 33554432;                 // bf16 8192x512 (aliases Xb)
constexpr size_t K_OFF = 41943040;                 // bf16 8192x512 (h first half)
constexpr size_t V_OFF = 50331648;                 // bf16 8192x512 (h second half)
constexpr size_t XB_OFF = Q_OFF;                   // bf16 X copy, dead before q written
constexpr size_t H_OFF = K_OFF;                    // bf16 8192x1024, dead before k/v written
constexpr size_t WTE_OFF = 58720256;               // bf16 1024x512
constexpr size_t WTS_OFF = WTE_OFF + 1048576;      // bf16 512x1024
constexpr size_t WTQKV_OFF = WTS_OFF + 1048576;    // bf16 1536x512
// end = 62,390,272 bytes

extern "C" void kernel_launch(void* const* d_in, const int* in_sizes, int n_in,
                              void* d_out, int out_size, void* d_ws, size_t ws_size,
                              hipStream_t stream) {
  const float* X = (const float*)d_in[0];
  const float* pos = (const float*)d_in[1];
  const float* W_expand = (const float*)d_in[2];
  const float* b_expand = (const float*)d_in[3];
  const float* W_squeeze = (const float*)d_in[4];
  const float* b_squeeze = (const float*)d_in[5];
  const float* gamma = (const float*)d_in[6];
  const float* beta = (const float*)d_in[7];
  const float* Wq = (const float*)d_in[8];
  const float* bq = (const float*)d_in[9];
  const float* Wk = (const float*)d_in[10];
  const float* bk = (const float*)d_in[11];
  const float* Wv = (const float*)d_in[12];
  const float* bv = (const float*)d_in[13];
  const float* alphap = (const float*)d_in[14];

  char* ws = (char*)d_ws;
  float* se = (float*)(ws + SE_OFF);
  bf16_t* sqb = (bf16_t*)(ws + SQB_OFF);
  bf16_t* ctxb = (bf16_t*)(ws + SQB_OFF);  // reuses sqb slot (sq dead after LN)
  bf16_t* seb = (bf16_t*)(ws + SEB_OFF);
  bf16_t* qb = (bf16_t*)(ws + Q_OFF);
  bf16_t* kb = (bf16_t*)(ws + K_OFF);
  bf16_t* vb = (bf16_t*)(ws + V_OFF);
  bf16_t* xbb = (bf16_t*)(ws + XB_OFF);
  bf16_t* hb = (bf16_t*)(ws + H_OFF);
  bf16_t* wtE = (bf16_t*)(ws + WTE_OFF);
  bf16_t* wtS = (bf16_t*)(ws + WTS_OFF);
  bf16_t* wtQKV = (bf16_t*)(ws + WTQKV_OFF);

  // X -> bf16
  cvt_k<<<Mrows * Dc / (256 * 8), 256, 0, stream>>>(X, xbb);
  // weights -> bf16 B^T
  wt_transpose_k<<<dim3(1024 / 32, 512 / 32), 256, 0, stream>>>(W_expand, wtE, 512, 1024);
  wt_transpose_k<<<dim3(512 / 32, 1024 / 32), 256, 0, stream>>>(W_squeeze, wtS, 1024, 512);
  wt_transpose_k<<<dim3(16, 16), 256, 0, stream>>>(Wq, wtQKV, 512, 512);
  wt_transpose_k<<<dim3(16, 16), 256, 0, stream>>>(Wk, wtQKV + 512 * 512, 512, 512);
  wt_transpose_k<<<dim3(16, 16), 256, 0, stream>>>(Wv, wtQKV + 2 * 512 * 512, 512, 512);

  // h = relu(X @ We + be)            [8192,1024] bf16
  gemm128_k<0><<<dim3(1024 / 128, Mrows / 128), 256, 0, stream>>>(
      xbb, wtE, b_expand, nullptr, nullptr, hb, nullptr, nullptr, 1024, 512);
  // sq = h @ Ws + bs                 [8192,512] bf16
  gemm128_k<1><<<dim3(512 / 128, Mrows / 128), 256, 0, stream>>>(
      hb, wtS, b_squeeze, nullptr, nullptr, sqb, nullptr, nullptr, 512, 1024);
  // se = LN(X + sq)  (fp32 + bf16 copy)
  ln_k<1><<<Mrows / 4, 256, 0, stream>>>(X, sqb, gamma, beta, se, seb);
  // q,k,v = se @ [Wq|Wk|Wv] + b      scattered bf16
  gemm128_k<2><<<dim3(1536 / 128, Mrows / 128), 256, 0, stream>>>(
      seb, wtQKV, bq, bk, bv, qb, kb, vb, 1536, 512);
  // ctx = attention(q,k,v,pos)       [8192,512] bf16 (reuses sqb slot)
  attn_k<<<dim3(Sc / 64, Hc, Bc), 256, 0, stream>>>(qb, kb, vb, pos, alphap, ctxb);
  // out = LN(se + ctx)
  ln_k<0><<<Mrows / 4, 256, 0, stream>>>(se, ctxb, gamma, beta, (float*)d_out, nullptr);

  (void)in_sizes; (void)n_in; (void)out_size; (void)ws_size;
}

// Round 3
// 259.716 us; speedup vs baseline: 1.3697x; 1.3697x over previous
//
#include <hip/hip_runtime.h>

typedef __bf16 bf16_t;
typedef __attribute__((ext_vector_type(8))) __bf16 bf16x8;
typedef __attribute__((ext_vector_type(4))) __bf16 bf16x4;
typedef __attribute__((ext_vector_type(4))) float f32x4;

constexpr int Bc = 4, Sc = 2048, Dc = 512, Hc = 4, HDc = 128;
constexpr int Mrows = Bc * Sc;  // 8192

__device__ inline void gl2lds(const void* g, void* l) {
  __builtin_amdgcn_global_load_lds(
      (__attribute__((address_space(1))) void*)g,
      (__attribute__((address_space(3))) void*)l, 16, 0, 0);
}

// ---------- weight transpose + cast: dst[n*K+k] = bf16(src[k*N+n]) ----------
__global__ __launch_bounds__(256) void wt_transpose_k(const float* __restrict__ src,
                                                      bf16_t* __restrict__ dst,
                                                      int K, int N) {
  __shared__ float tile[32][33];
  const int tx = threadIdx.x & 31, ty = threadIdx.x >> 5;
  const int n0 = blockIdx.x * 32, k0 = blockIdx.y * 32;
#pragma unroll
  for (int i = 0; i < 4; i++)
    tile[ty + i * 8][tx] = src[(long)(k0 + ty + i * 8) * N + n0 + tx];
  __syncthreads();
#pragma unroll
  for (int i = 0; i < 4; i++)
    dst[(long)(n0 + ty + i * 8) * K + k0 + tx] = (bf16_t)tile[tx][ty + i * 8];
}

// ---------- fp32 -> bf16 cast (8 elements/thread) ----------
__global__ __launch_bounds__(256) void cvt_k(const float* __restrict__ x,
                                             bf16_t* __restrict__ y) {
  const long i = ((long)blockIdx.x * 256 + threadIdx.x) * 8;
  const float4 a = *(const float4*)(x + i);
  const float4 c = *(const float4*)(x + i + 4);
  bf16x8 o;
  o[0] = (bf16_t)a.x; o[1] = (bf16_t)a.y; o[2] = (bf16_t)a.z; o[3] = (bf16_t)a.w;
  o[4] = (bf16_t)c.x; o[5] = (bf16_t)c.y; o[6] = (bf16_t)c.z; o[7] = (bf16_t)c.w;
  *(bf16x8*)(y + i) = o;
}

// ---------- pack positions: pos2[s] = (x,y,z,0) float4 ----------
__global__ __launch_bounds__(256) void pospack_k(const float* __restrict__ pos,
                                                 float* __restrict__ pos2) {
  const int i = blockIdx.x * 256 + threadIdx.x;
  const float x = pos[(long)i * 3], y = pos[(long)i * 3 + 1], z = pos[(long)i * 3 + 2];
  float4 o; o.x = x; o.y = y; o.z = z; o.w = 0.f;
  *(float4*)(pos2 + (long)i * 4) = o;
}

// ---------- m97-style 128x128 MFMA GEMM, A bf16 [M][K], Bt bf16 [N][K] ----------
// OMODE: 0 = relu+bias -> bf16 ; 1 = bias -> bf16 ; 2 = qkv scatter bf16
template <int OMODE>
__global__ __launch_bounds__(256, 2) void gemm128_k(
    const bf16_t* __restrict__ A, const bf16_t* __restrict__ Bt,
    const float* __restrict__ bias0, const float* __restrict__ bias1,
    const float* __restrict__ bias2, void* __restrict__ out0,
    void* __restrict__ out1, void* __restrict__ out2, int N, int K) {
  __shared__ bf16_t As[128 * 32];  // row-major [128][32], unpadded (global_load_lds)
  __shared__ bf16_t Bs[128 * 32];
  const int t = threadIdx.x;
  const int n0 = blockIdx.x * 128, m0 = blockIdx.y * 128;
  const int lane = t & 63, wave = t >> 6;
  const int quad = lane >> 4, ln = lane & 15;
  const int wm = wave >> 1, wn = wave & 1;  // 2x2 waves, 64x64 each
  const int srow = wave * 16 + (lane >> 2);
  const int scol = (lane & 3) * 8;
  const bf16_t* aseg = A + (long)(m0 + srow) * K + scol;
  const bf16_t* bseg = Bt + (long)(n0 + srow) * K + scol;
  bf16_t* asl = &As[(wave * 16) * 32];  // wave-uniform LDS base
  bf16_t* bsl = &Bs[(wave * 16) * 32];
  f32x4 acc[4][4] = {};
  for (int k0 = 0; k0 < K; k0 += 32) {
#pragma unroll
    for (int i = 0; i < 2; i++) {
      gl2lds(aseg + (long)i * 64 * K + k0, asl + i * 64 * 32);
      gl2lds(bseg + (long)i * 64 * K + k0, bsl + i * 64 * 32);
    }
    __syncthreads();
    bf16x8 af[4], bfr[4];
#pragma unroll
    for (int mt = 0; mt < 4; mt++)
      af[mt] = *(const bf16x8*)&As[(wm * 64 + mt * 16 + ln) * 32 + quad * 8];
#pragma unroll
    for (int nt = 0; nt < 4; nt++)
      bfr[nt] = *(const bf16x8*)&Bs[(wn * 64 + nt * 16 + ln) * 32 + quad * 8];
#pragma unroll
    for (int mt = 0; mt < 4; mt++)
#pragma unroll
      for (int nt = 0; nt < 4; nt++)
        acc[mt][nt] = __builtin_amdgcn_mfma_f32_16x16x32_bf16(af[mt], bfr[nt],
                                                              acc[mt][nt], 0, 0, 0);
    __syncthreads();
  }
#pragma unroll
  for (int nt = 0; nt < 4; nt++) {
    const int gcol = n0 + wn * 64 + nt * 16 + ln;
    if constexpr (OMODE == 0 || OMODE == 1) {
      const float bv = bias0[gcol];
      bf16_t* o = (bf16_t*)out0;
#pragma unroll
      for (int mt = 0; mt < 4; mt++)
#pragma unroll
        for (int r = 0; r < 4; r++) {
          const int grow = m0 + wm * 64 + mt * 16 + quad * 4 + r;
          float vv = acc[mt][nt][r] + bv;
          if constexpr (OMODE == 0) vv = vv > 0.f ? vv : 0.f;
          o[(long)grow * N + gcol] = (bf16_t)vv;
        }
    } else {
      const int which = gcol >> 9, n = gcol & 511;
      const int hh = n >> 7, hd = n & 127;
      const float bv = (which == 0 ? bias0 : which == 1 ? bias1 : bias2)[n];
      bf16_t* o = (bf16_t*)(which == 0 ? out0 : which == 1 ? out1 : out2);
#pragma unroll
      for (int mt = 0; mt < 4; mt++)
#pragma unroll
        for (int r = 0; r < 4; r++) {
          const int grow = m0 + wm * 64 + mt * 16 + quad * 4 + r;
          const int b = grow >> 11, s = grow & 2047;
          const float vv = acc[mt][nt][r] + bv;
          long idx;
          if (which == 2)  // v stored transposed [b,h,hd,s]
            idx = ((long)(b * Hc + hh) * HDc + hd) * Sc + s;
          else             // q,k stored [b,h,s,hd]
            idx = ((long)(b * Hc + hh) * Sc + s) * HDc + hd;
          o[idx] = (bf16_t)vv;
        }
    }
  }
}

// ---------- LayerNorm(xa_fp32 + xb_bf16): one wave per row of 512 ----------
template <int DUAL>
__global__ __launch_bounds__(256) void ln_k(const float* __restrict__ xa,
                                            const bf16_t* __restrict__ xb,
                                            const float* __restrict__ gamma,
                                            const float* __restrict__ beta,
                                            float* __restrict__ out,
                                            bf16_t* __restrict__ outb) {
  const int wave = threadIdx.x >> 6, lane = threadIdx.x & 63;
  const long row = (long)blockIdx.x * 4 + wave;
  const float* a = xa + row * Dc;
  const bf16_t* bp = xb + row * Dc;
  float vv[8];
  float s = 0.f, s2 = 0.f;
#pragma unroll
  for (int i = 0; i < 2; i++) {
    const float4 va = *(const float4*)(a + lane * 4 + i * 256);
    const bf16x4 vb = *(const bf16x4*)(bp + lane * 4 + i * 256);
    const float xs[4] = {va.x, va.y, va.z, va.w};
#pragma unroll
    for (int j = 0; j < 4; j++) {
      const float x = xs[j] + (float)vb[j];
      vv[i * 4 + j] = x;
      s += x;
      s2 += x * x;
    }
  }
#pragma unroll
  for (int off = 1; off < 64; off <<= 1) {
    s += __shfl_xor(s, off, 64);
    s2 += __shfl_xor(s2, off, 64);
  }
  const float mu = s * (1.f / Dc);
  const float var = s2 * (1.f / Dc) - mu * mu;
  const float rstd = rsqrtf(var + 1e-5f);
#pragma unroll
  for (int i = 0; i < 2; i++)
#pragma unroll
    for (int j = 0; j < 4; j++) {
      const int col = lane * 4 + i * 256 + j;
      const float o = (vv[i * 4 + j] - mu) * rstd * gamma[col] + beta[col];
      out[row * Dc + col] = o;
      if constexpr (DUAL) outb[row * Dc + col] = (bf16_t)o;
    }
}

// ---------- flash attention: dbuf gl2lds staging + XOR swizzle, one-pass softmax ----
// q,k: bf16 [b,h,s,hd]; v: bf16 [b,h,hd,s]; pos2: float4/key; ctx: bf16 [b,s,D]
__global__ __launch_bounds__(256, 2) void attn_k(const bf16_t* __restrict__ q,
                                                 const bf16_t* __restrict__ k,
                                                 const bf16_t* __restrict__ v,
                                                 const float* __restrict__ pos2,
                                                 const float* __restrict__ alphap,
                                                 bf16_t* __restrict__ ctx) {
  __shared__ bf16_t Ks[2][64 * 128];   // [key][hd], col-groups XOR-swizzled by row&7
  __shared__ bf16_t Vts[2][128 * 64];  // [hd][key], col-groups XOR-swizzled by row&7
  __shared__ float pk[2][64][4];       // key positions (x,y,z,0)
  __shared__ bf16_t Ps[4][16][72];     // per-wave P: [qrow][key]
  const int t = threadIdx.x;
  const int qt = blockIdx.x, h = blockIdx.y, b = blockIdx.z;
  const int q0 = qt * 64;
  const int wave = t >> 6, lane = t & 63, quad = lane >> 4, ln = lane & 15;
  const int ln7 = ln & 7;
  const float l2e = 1.4426950408889634f;
  const float scale_l2 = 0.08838834764831845f * l2e;  // (1/sqrt(128))*log2(e)
  const float alpha_l2 = alphap[0] * l2e;
  const bf16_t* kbase = k + (long)(b * Hc + h) * Sc * HDc;
  const bf16_t* vbase = v + (long)(b * Hc + h) * HDc * Sc;

  // Q fragments + q-positions in registers
  bf16x8 qf[4];
#pragma unroll
  for (int kc = 0; kc < 4; kc++)
    qf[kc] = *(const bf16x8*)(q + ((long)(b * Hc + h) * Sc + q0 + wave * 16 + ln) * HDc +
                              kc * 32 + quad * 8);
  float pqx[4], pqy[4], pqz[4];
#pragma unroll
  for (int r = 0; r < 4; r++) {
    const float4 p = *(const float4*)(pos2 + ((long)b * Sc + q0 + wave * 16 + quad * 4 + r) * 4);
    pqx[r] = p.x; pqy[r] = p.y; pqz[r] = p.z;
  }

  // async staging: per wave 4 K-chunks + 4 V-chunks of 64 lanes x 16B each
  const int krw = wave * 16 + (lane >> 4);  // + 4i
  const int kg = lane & 15;
  const int vrw = wave * 32 + (lane >> 3);  // + 8i
  const int vg = lane & 7;
  auto stage = [&](int buf, int kt) {
#pragma unroll
    for (int i = 0; i < 4; i++) {
      const int row = krw + i * 4;  // tile-local key row
      gl2lds(kbase + (long)(kt * 64 + row) * HDc + (kg ^ (row & 7)) * 8,
             &Ks[buf][wave * 2048 + i * 512]);
    }
#pragma unroll
    for (int i = 0; i < 4; i++) {
      const int row = vrw + i * 8;  // tile-local hd row
      gl2lds(vbase + (long)row * Sc + kt * 64 + (vg ^ (row & 7)) * 8,
             &Vts[buf][wave * 2048 + i * 512]);
    }
    if (wave == 0)
      gl2lds(pos2 + ((long)b * Sc + kt * 64) * 4, &pk[buf][0][0]);
  };
  stage(0, 0);

  float rs[4] = {0.f, 0.f, 0.f, 0.f};
  f32x4 acc_o[8] = {};

  for (int kt = 0; kt < Sc / 64; kt++) {
    const int cur = kt & 1;
    __syncthreads();  // drains vmcnt: buf[cur] ready; readers of buf[1-cur] done
    if (kt < Sc / 64 - 1) stage(1 - cur, kt + 1);  // async, overlaps compute below

    // S = Q @ K^T (16 q-rows x 64 keys per wave)
    f32x4 sacc[4] = {};
#pragma unroll
    for (int kc = 0; kc < 4; kc++)
#pragma unroll
      for (int ct = 0; ct < 4; ct++) {
        const bf16x8 bfv = *(const bf16x8*)&Ks[cur][(ct * 16 + ln) * 128 +
                                                    ((kc * 4 + quad) ^ ln7) * 8];
        sacc[ct] = __builtin_amdgcn_mfma_f32_16x16x32_bf16(qf[kc], bfv, sacc[ct], 0, 0, 0);
      }
    // un-normalized softmax: p = 2^(s*scale*l2e - alpha*l2e*d2); lane-local sum
#pragma unroll
    for (int ct = 0; ct < 4; ct++) {
      const int kk = ct * 16 + ln;
      const float4 pkv = *(const float4*)&pk[cur][kk][0];
#pragma unroll
      for (int r = 0; r < 4; r++) {
        const float dx = pqx[r] - pkv.x, dy = pqy[r] - pkv.y, dz = pqz[r] - pkv.z;
        const float d2 = dx * dx + dy * dy + dz * dz;
        const float p = __builtin_amdgcn_exp2f(sacc[ct][r] * scale_l2 - alpha_l2 * d2);
        rs[r] += p;
        Ps[wave][quad * 4 + r][kk] = (bf16_t)p;  // wave-private, in-order DS
      }
    }
    // O += P @ V
#pragma unroll
    for (int s2 = 0; s2 < 2; s2++) {
      const bf16x8 pf = *(const bf16x8*)&Ps[wave][ln][s2 * 32 + quad * 8];
#pragma unroll
      for (int nt = 0; nt < 8; nt++) {
        const bf16x8 vf = *(const bf16x8*)&Vts[cur][(nt * 16 + ln) * 64 +
                                                    ((s2 * 4 + quad) ^ ln7) * 8];
        acc_o[nt] = __builtin_amdgcn_mfma_f32_16x16x32_bf16(pf, vf, acc_o[nt], 0, 0, 0);
      }
    }
  }

  // one final 16-lane reduction of the softmax denominator
#pragma unroll
  for (int off = 1; off < 16; off <<= 1)
#pragma unroll
    for (int r = 0; r < 4; r++) rs[r] += __shfl_xor(rs[r], off, 64);
  float rinv[4];
#pragma unroll
  for (int r = 0; r < 4; r++) rinv[r] = 1.f / rs[r];
#pragma unroll
  for (int nt = 0; nt < 8; nt++)
#pragma unroll
    for (int r = 0; r < 4; r++) {
      const int qrow = wave * 16 + quad * 4 + r;
      ctx[((long)b * Sc + q0 + qrow) * Dc + h * HDc + nt * 16 + ln] =
          (bf16_t)(acc_o[nt][r] * rinv[r]);
    }
}

// ---------------- workspace layout (bytes) ----------------
constexpr size_t SE_OFF = 0;                       // fp32 8192x512   (16 MB)
constexpr size_t SQB_OFF = 16777216;               // bf16 8192x512: squeeze out, later ctx
constexpr size_t SEB_OFF = 25165824;               // bf16 8192x512: se bf16; later pos2
constexpr size_t Q_OFF = 33554432;                 // bf16 8192x512 (aliases Xb)
constexpr size_t K_OFF = 41943040;                 // bf16 8192x512 (h first half)
constexpr size_t V_OFF = 50331648;                 // bf16 8192x512 (h second half)
constexpr size_t XB_OFF = Q_OFF;                   // bf16 X copy, dead before q written
constexpr size_t H_OFF = K_OFF;                    // bf16 8192x1024, dead before k/v written
constexpr size_t POS2_OFF = SEB_OFF;               // float4 x 8192 = 128 KB, after seb dead
constexpr size_t WTE_OFF = 58720256;               // bf16 1024x512
constexpr size_t WTS_OFF = WTE_OFF + 1048576;      // bf16 512x1024
constexpr size_t WTQKV_OFF = WTS_OFF + 1048576;    // bf16 1536x512
// end = 62,390,272 bytes

extern "C" void kernel_launch(void* const* d_in, const int* in_sizes, int n_in,
                              void* d_out, int out_size, void* d_ws, size_t ws_size,
                              hipStream_t stream) {
  const float* X = (const float*)d_in[0];
  const float* pos = (const float*)d_in[1];
  const float* W_expand = (const float*)d_in[2];
  const float* b_expand = (const float*)d_in[3];
  const float* W_squeeze = (const float*)d_in[4];
  const float* b_squeeze = (const float*)d_in[5];
  const float* gamma = (const float*)d_in[6];
  const float* beta = (const float*)d_in[7];
  const float* Wq = (const float*)d_in[8];
  const float* bq = (const float*)d_in[9];
  const float* Wk = (const float*)d_in[10];
  const float* bk = (const float*)d_in[11];
  const float* Wv = (const float*)d_in[12];
  const float* bv = (const float*)d_in[13];
  const float* alphap = (const float*)d_in[14];

  char* ws = (char*)d_ws;
  float* se = (float*)(ws + SE_OFF);
  bf16_t* sqb = (bf16_t*)(ws + SQB_OFF);
  bf16_t* ctxb = (bf16_t*)(ws + SQB_OFF);  // reuses sqb slot (sq dead after LN)
  bf16_t* seb = (bf16_t*)(ws + SEB_OFF);
  float* pos2 = (float*)(ws + POS2_OFF);   // written after seb is dead
  bf16_t* qb = (bf16_t*)(ws + Q_OFF);
  bf16_t* kb = (bf16_t*)(ws + K_OFF);
  bf16_t* vb = (bf16_t*)(ws + V_OFF);
  bf16_t* xbb = (bf16_t*)(ws + XB_OFF);
  bf16_t* hb = (bf16_t*)(ws + H_OFF);
  bf16_t* wtE = (bf16_t*)(ws + WTE_OFF);
  bf16_t* wtS = (bf16_t*)(ws + WTS_OFF);
  bf16_t* wtQKV = (bf16_t*)(ws + WTQKV_OFF);

  // X -> bf16
  cvt_k<<<Mrows * Dc / (256 * 8), 256, 0, stream>>>(X, xbb);
  // weights -> bf16 B^T
  wt_transpose_k<<<dim3(1024 / 32, 512 / 32), 256, 0, stream>>>(W_expand, wtE, 512, 1024);
  wt_transpose_k<<<dim3(512 / 32, 1024 / 32), 256, 0, stream>>>(W_squeeze, wtS, 1024, 512);
  wt_transpose_k<<<dim3(16, 16), 256, 0, stream>>>(Wq, wtQKV, 512, 512);
  wt_transpose_k<<<dim3(16, 16), 256, 0, stream>>>(Wk, wtQKV + 512 * 512, 512, 512);
  wt_transpose_k<<<dim3(16, 16), 256, 0, stream>>>(Wv, wtQKV + 2 * 512 * 512, 512, 512);

  // h = relu(X @ We + be)            [8192,1024] bf16
  gemm128_k<0><<<dim3(1024 / 128, Mrows / 128), 256, 0, stream>>>(
      xbb, wtE, b_expand, nullptr, nullptr, hb, nullptr, nullptr, 1024, 512);
  // sq = h @ Ws + bs                 [8192,512] bf16
  gemm128_k<1><<<dim3(512 / 128, Mrows / 128), 256, 0, stream>>>(
      hb, wtS, b_squeeze, nullptr, nullptr, sqb, nullptr, nullptr, 512, 1024);
  // se = LN(X + sq)  (fp32 + bf16 copy)
  ln_k<1><<<Mrows / 4, 256, 0, stream>>>(X, sqb, gamma, beta, se, seb);
  // q,k,v = se @ [Wq|Wk|Wv] + b      scattered bf16
  gemm128_k<2><<<dim3(1536 / 128, Mrows / 128), 256, 0, stream>>>(
      seb, wtQKV, bq, bk, bv, qb, kb, vb, 1536, 512);
  // pack positions (seb now dead; pos2 aliases it)
  pospack_k<<<Mrows / 256, 256, 0, stream>>>(pos, pos2);
  // ctx = attention(q,k,v,pos2)      [8192,512] bf16 (reuses sqb slot)
  attn_k<<<dim3(Sc / 64, Hc, Bc), 256, 0, stream>>>(qb, kb, vb, pos2, alphap, ctxb);
  // out = LN(se + ctx)
  ln_k<0><<<Mrows / 4, 256, 0, stream>>>(se, ctxb, gamma, beta, (float*)d_out, nullptr);

  (void)in_sizes; (void)n_in; (void)out_size; (void)ws_size;
}

// Round 4
// 243.424 us; speedup vs baseline: 1.4614x; 1.0669x over previous
//
#include <hip/hip_runtime.h>

typedef __bf16 bf16_t;
typedef __attribute__((ext_vector_type(8))) __bf16 bf16x8;
typedef __attribute__((ext_vector_type(4))) __bf16 bf16x4;
typedef __attribute__((ext_vector_type(4))) float f32x4;

constexpr int Bc = 4, Sc = 2048, Dc = 512, Hc = 4, HDc = 128;
constexpr int Mrows = Bc * Sc;  // 8192

__device__ inline void gl2lds(const void* g, void* l) {
  __builtin_amdgcn_global_load_lds(
      (__attribute__((address_space(1))) void*)g,
      (__attribute__((address_space(3))) void*)l, 16, 0, 0);
}

// ---------- fused prep: X->bf16 cast (blocks 0..2047) + 5 weight transposes ----------
__global__ __launch_bounds__(256) void prep_k(
    const float* __restrict__ X, bf16_t* __restrict__ xb,
    const float* __restrict__ We, bf16_t* __restrict__ wtE,
    const float* __restrict__ Ws, bf16_t* __restrict__ wtS,
    const float* __restrict__ Wq, const float* __restrict__ Wk,
    const float* __restrict__ Wv, bf16_t* __restrict__ wtQKV) {
  const int bid = blockIdx.x;
  if (bid < 2048) {  // cvt: 2048 blocks x 256 thr x 8 elem = 8192*512
    const long i = ((long)bid * 256 + threadIdx.x) * 8;
    const float4 a = *(const float4*)(X + i);
    const float4 c = *(const float4*)(X + i + 4);
    bf16x8 o;
    o[0] = (bf16_t)a.x; o[1] = (bf16_t)a.y; o[2] = (bf16_t)a.z; o[3] = (bf16_t)a.w;
    o[4] = (bf16_t)c.x; o[5] = (bf16_t)c.y; o[6] = (bf16_t)c.z; o[7] = (bf16_t)c.w;
    *(bf16x8*)(xb + i) = o;
    return;
  }
  // transposes: dst[n*K+k] = bf16(src[k*N+n]) in 32x32 tiles
  __shared__ float tile[32][33];
  const float* src; bf16_t* dst; int K, N, local;
  if (bid < 2560)      { src = We; dst = wtE; K = 512;  N = 1024; local = bid - 2048; }
  else if (bid < 3072) { src = Ws; dst = wtS; K = 1024; N = 512;  local = bid - 2560; }
  else if (bid < 3328) { src = Wq; dst = wtQKV;          K = 512; N = 512; local = bid - 3072; }
  else if (bid < 3584) { src = Wk; dst = wtQKV + 262144; K = 512; N = 512; local = bid - 3328; }
  else                 { src = Wv; dst = wtQKV + 524288; K = 512; N = 512; local = bid - 3584; }
  const int nb = N / 32;
  const int n0 = (local % nb) * 32, k0 = (local / nb) * 32;
  const int tx = threadIdx.x & 31, ty = threadIdx.x >> 5;
#pragma unroll
  for (int i = 0; i < 4; i++)
    tile[ty + i * 8][tx] = src[(long)(k0 + ty + i * 8) * N + n0 + tx];
  __syncthreads();
#pragma unroll
  for (int i = 0; i < 4; i++)
    dst[(long)(n0 + ty + i * 8) * K + k0 + tx] = (bf16_t)tile[tx][ty + i * 8];
}

// ---------- pack positions: pos2[s] = (x, y, z, -alphaL2*|p|^2) ----------
__global__ __launch_bounds__(256) void pospack_k(const float* __restrict__ pos,
                                                 const float* __restrict__ alphap,
                                                 float* __restrict__ pos2) {
  const float aL = alphap[0] * 1.4426950408889634f;
  const int i = blockIdx.x * 256 + threadIdx.x;
  const float x = pos[(long)i * 3], y = pos[(long)i * 3 + 1], z = pos[(long)i * 3 + 2];
  float4 o; o.x = x; o.y = y; o.z = z; o.w = -aL * (x * x + y * y + z * z);
  *(float4*)(pos2 + (long)i * 4) = o;
}

// ---------- 128x128 MFMA GEMM, BK=64, A bf16 [M][K], Bt bf16 [N][K] ----------
// OMODE: 0 = relu+bias -> bf16 ; 1 = bias -> bf16 ; 2 = qkv scatter bf16
template <int OMODE>
__global__ __launch_bounds__(256, 3) void gemm128_k(
    const bf16_t* __restrict__ A, const bf16_t* __restrict__ Bt,
    const float* __restrict__ bias0, const float* __restrict__ bias1,
    const float* __restrict__ bias2, void* __restrict__ out0,
    void* __restrict__ out1, void* __restrict__ out2, int N, int K) {
  __shared__ bf16_t As[128 * 64];  // [128][64] row-major, unpadded (gl2lds)
  __shared__ bf16_t Bs[128 * 64];
  const int t = threadIdx.x;
  const int n0 = blockIdx.x * 128, m0 = blockIdx.y * 128;
  const int lane = t & 63, wave = t >> 6;
  const int quad = lane >> 4, ln = lane & 15;
  const int wm = wave >> 1, wn = wave & 1;  // 2x2 waves, 64x64 each
  const int srow = wave * 32 + (lane >> 3);  // + 8i
  const int sgrp = lane & 7;
  const bf16_t* aseg = A + (long)(m0 + srow) * K + sgrp * 8;
  const bf16_t* bseg = Bt + (long)(n0 + srow) * K + sgrp * 8;
  bf16_t* asl = &As[(wave * 32) * 64];  // wave-uniform LDS base
  bf16_t* bsl = &Bs[(wave * 32) * 64];
  f32x4 acc[4][4] = {};
  for (int k0 = 0; k0 < K; k0 += 64) {
#pragma unroll
    for (int i = 0; i < 4; i++) {
      gl2lds(aseg + (long)i * 8 * K + k0, asl + i * 8 * 64);
      gl2lds(bseg + (long)i * 8 * K + k0, bsl + i * 8 * 64);
    }
    __syncthreads();
#pragma unroll
    for (int kc = 0; kc < 2; kc++) {
      bf16x8 af[4], bfr[4];
#pragma unroll
      for (int mt = 0; mt < 4; mt++)
        af[mt] = *(const bf16x8*)&As[(wm * 64 + mt * 16 + ln) * 64 + kc * 32 + quad * 8];
#pragma unroll
      for (int nt = 0; nt < 4; nt++)
        bfr[nt] = *(const bf16x8*)&Bs[(wn * 64 + nt * 16 + ln) * 64 + kc * 32 + quad * 8];
#pragma unroll
      for (int mt = 0; mt < 4; mt++)
#pragma unroll
        for (int nt = 0; nt < 4; nt++)
          acc[mt][nt] = __builtin_amdgcn_mfma_f32_16x16x32_bf16(af[mt], bfr[nt],
                                                                acc[mt][nt], 0, 0, 0);
    }
    __syncthreads();
  }
#pragma unroll
  for (int nt = 0; nt < 4; nt++) {
    const int gcol = n0 + wn * 64 + nt * 16 + ln;
    if constexpr (OMODE == 0 || OMODE == 1) {
      const float bv = bias0[gcol];
      bf16_t* o = (bf16_t*)out0;
#pragma unroll
      for (int mt = 0; mt < 4; mt++)
#pragma unroll
        for (int r = 0; r < 4; r++) {
          const int grow = m0 + wm * 64 + mt * 16 + quad * 4 + r;
          float vv = acc[mt][nt][r] + bv;
          if constexpr (OMODE == 0) vv = vv > 0.f ? vv : 0.f;
          o[(long)grow * N + gcol] = (bf16_t)vv;
        }
    } else {
      const int which = gcol >> 9, n = gcol & 511;
      const int hh = n >> 7, hd = n & 127;
      const float bv = (which == 0 ? bias0 : which == 1 ? bias1 : bias2)[n];
      bf16_t* o = (bf16_t*)(which == 0 ? out0 : which == 1 ? out1 : out2);
#pragma unroll
      for (int mt = 0; mt < 4; mt++)
#pragma unroll
        for (int r = 0; r < 4; r++) {
          const int grow = m0 + wm * 64 + mt * 16 + quad * 4 + r;
          const int b = grow >> 11, s = grow & 2047;
          const float vv = acc[mt][nt][r] + bv;
          long idx;
          if (which == 2)  // v stored transposed [b,h,hd,s]
            idx = ((long)(b * Hc + hh) * HDc + hd) * Sc + s;
          else             // q,k stored [b,h,s,hd]
            idx = ((long)(b * Hc + hh) * Sc + s) * HDc + hd;
          o[idx] = (bf16_t)vv;
        }
    }
  }
}

// ---------- LayerNorm(xa_fp32 + xb_bf16): one wave per row of 512 ----------
template <int DUAL>
__global__ __launch_bounds__(256) void ln_k(const float* __restrict__ xa,
                                            const bf16_t* __restrict__ xb,
                                            const float* __restrict__ gamma,
                                            const float* __restrict__ beta,
                                            float* __restrict__ out,
                                            bf16_t* __restrict__ outb) {
  const int wave = threadIdx.x >> 6, lane = threadIdx.x & 63;
  const long row = (long)blockIdx.x * 4 + wave;
  const float* a = xa + row * Dc;
  const bf16_t* bp = xb + row * Dc;
  float vv[8];
  float s = 0.f, s2 = 0.f;
#pragma unroll
  for (int i = 0; i < 2; i++) {
    const float4 va = *(const float4*)(a + lane * 4 + i * 256);
    const bf16x4 vb = *(const bf16x4*)(bp + lane * 4 + i * 256);
    const float xs[4] = {va.x, va.y, va.z, va.w};
#pragma unroll
    for (int j = 0; j < 4; j++) {
      const float x = xs[j] + (float)vb[j];
      vv[i * 4 + j] = x;
      s += x;
      s2 += x * x;
    }
  }
#pragma unroll
  for (int off = 1; off < 64; off <<= 1) {
    s += __shfl_xor(s, off, 64);
    s2 += __shfl_xor(s2, off, 64);
  }
  const float mu = s * (1.f / Dc);
  const float var = s2 * (1.f / Dc) - mu * mu;
  const float rstd = rsqrtf(var + 1e-5f);
#pragma unroll
  for (int i = 0; i < 2; i++)
#pragma unroll
    for (int j = 0; j < 4; j++) {
      const int col = lane * 4 + i * 256 + j;
      const float o = (vv[i * 4 + j] - mu) * rstd * gamma[col] + beta[col];
      out[row * Dc + col] = o;
      if constexpr (DUAL) outb[row * Dc + col] = (bf16_t)o;
    }
}

// ---------- flash attention: dbuf gl2lds staging, folded-bias one-pass softmax ----
// q,k: bf16 [b,h,s,hd]; v: bf16 [b,h,hd,s]; pos2: (x,y,z,-aL*n); ctx: bf16 [b,s,D]
__global__ __launch_bounds__(256, 2) void attn_k(const bf16_t* __restrict__ q,
                                                 const bf16_t* __restrict__ k,
                                                 const bf16_t* __restrict__ v,
                                                 const float* __restrict__ pos2,
                                                 const float* __restrict__ alphap,
                                                 bf16_t* __restrict__ ctx) {
  __shared__ bf16_t Ks[2][64 * 128];   // [key][hd], col-groups XOR-swizzled by row&7
  __shared__ bf16_t Vts[2][128 * 64];  // [hd][key], col-groups XOR-swizzled by row&7
  __shared__ float pk[2][64][4];       // key positions (x,y,z,-aL*n)
  __shared__ bf16_t Ps[4][16][72];     // per-wave P: [qrow][key]
  const int t = threadIdx.x;
  const int qt = blockIdx.x, h = blockIdx.y, b = blockIdx.z;
  const int q0 = qt * 64;
  const int wave = t >> 6, lane = t & 63, quad = lane >> 4, ln = lane & 15;
  const int ln7 = ln & 7;
  const float l2e = 1.4426950408889634f;
  const float scale_l2 = 0.08838834764831845f * l2e;  // (1/sqrt(128))*log2(e)
  const float aL2 = alphap[0] * l2e;
  const float twoaL = 2.f * aL2;
  const bf16_t* kbase = k + (long)(b * Hc + h) * Sc * HDc;
  const bf16_t* vbase = v + (long)(b * Hc + h) * HDc * Sc;

  // Q fragments + q-positions in registers (q xyz prescaled by 2*aL2; w = -aL2*|q|^2)
  bf16x8 qf[4];
#pragma unroll
  for (int kc = 0; kc < 4; kc++)
    qf[kc] = *(const bf16x8*)(q + ((long)(b * Hc + h) * Sc + q0 + wave * 16 + ln) * HDc +
                              kc * 32 + quad * 8);
  float pqx[4], pqy[4], pqz[4], pqw[4];
#pragma unroll
  for (int r = 0; r < 4; r++) {
    const float4 p = *(const float4*)(pos2 + ((long)b * Sc + q0 + wave * 16 + quad * 4 + r) * 4);
    pqx[r] = twoaL * p.x; pqy[r] = twoaL * p.y; pqz[r] = twoaL * p.z; pqw[r] = p.w;
  }

  // async staging: per wave 4 K-chunks + 4 V-chunks of 64 lanes x 16B each
  const int krw = wave * 16 + (lane >> 4);  // + 4i
  const int kg = lane & 15;
  const int vrw = wave * 32 + (lane >> 3);  // + 8i
  const int vg = lane & 7;
  const bf16_t* kcur = kbase;
  const bf16_t* vcur = vbase;
  const float* pcur = pos2 + (long)b * Sc * 4;
  auto stage = [&](int buf) {
#pragma unroll
    for (int i = 0; i < 4; i++) {
      const int row = krw + i * 4;
      gl2lds(kcur + (long)row * HDc + (kg ^ (row & 7)) * 8, &Ks[buf][wave * 2048 + i * 512]);
    }
#pragma unroll
    for (int i = 0; i < 4; i++) {
      const int row = vrw + i * 8;
      gl2lds(vcur + (long)row * Sc + (vg ^ (row & 7)) * 8, &Vts[buf][wave * 2048 + i * 512]);
    }
    if (wave == 0) gl2lds(pcur, &pk[buf][0][0]);
  };
  stage(0);
  kcur += 64 * HDc; vcur += 64; pcur += 256;

  float rs[4] = {0.f, 0.f, 0.f, 0.f};
  f32x4 acc_o[8] = {};

  for (int kt = 0; kt < Sc / 64; kt++) {
    const int cur = kt & 1;
    __syncthreads();  // drains vmcnt: buf[cur] ready; readers of buf[1-cur] done
    if (kt < Sc / 64 - 1) {
      stage(1 - cur);  // async, overlaps compute below
      kcur += 64 * HDc; vcur += 64; pcur += 256;
    }

    // S = Q @ K^T (16 q-rows x 64 keys per wave)
    f32x4 sacc[4] = {};
#pragma unroll
    for (int kc = 0; kc < 4; kc++)
#pragma unroll
      for (int ct = 0; ct < 4; ct++) {
        const bf16x8 bfv = *(const bf16x8*)&Ks[cur][(ct * 16 + ln) * 128 +
                                                    ((kc * 4 + quad) ^ ln7) * 8];
        sacc[ct] = __builtin_amdgcn_mfma_f32_16x16x32_bf16(qf[kc], bfv, sacc[ct], 0, 0, 0);
      }
    // p = 2^(s*scale_l2 + pq.w + pk.w + pq_scaled . pk); lane-local denom sum
#pragma unroll
    for (int ct = 0; ct < 4; ct++) {
      const int kk = ct * 16 + ln;
      const float4 pkv = *(const float4*)&pk[cur][kk][0];
#pragma unroll
      for (int r = 0; r < 4; r++) {
        float base = pqw[r] + pkv.w;
        base = __builtin_fmaf(pqx[r], pkv.x, base);
        base = __builtin_fmaf(pqy[r], pkv.y, base);
        base = __builtin_fmaf(pqz[r], pkv.z, base);
        const float p = __builtin_amdgcn_exp2f(__builtin_fmaf(sacc[ct][r], scale_l2, base));
        rs[r] += p;
        Ps[wave][quad * 4 + r][kk] = (bf16_t)p;  // wave-private, in-order DS
      }
    }
    // O += P @ V
#pragma unroll
    for (int s2 = 0; s2 < 2; s2++) {
      const bf16x8 pf = *(const bf16x8*)&Ps[wave][ln][s2 * 32 + quad * 8];
#pragma unroll
      for (int nt = 0; nt < 8; nt++) {
        const bf16x8 vf = *(const bf16x8*)&Vts[cur][(nt * 16 + ln) * 64 +
                                                    ((s2 * 4 + quad) ^ ln7) * 8];
        acc_o[nt] = __builtin_amdgcn_mfma_f32_16x16x32_bf16(pf, vf, acc_o[nt], 0, 0, 0);
      }
    }
  }

  // one final 16-lane reduction of the softmax denominator
#pragma unroll
  for (int off = 1; off < 16; off <<= 1)
#pragma unroll
    for (int r = 0; r < 4; r++) rs[r] += __shfl_xor(rs[r], off, 64);
  float rinv[4];
#pragma unroll
  for (int r = 0; r < 4; r++) rinv[r] = 1.f / rs[r];
#pragma unroll
  for (int nt = 0; nt < 8; nt++)
#pragma unroll
    for (int r = 0; r < 4; r++) {
      const int qrow = wave * 16 + quad * 4 + r;
      ctx[((long)b * Sc + q0 + qrow) * Dc + h * HDc + nt * 16 + ln] =
          (bf16_t)(acc_o[nt][r] * rinv[r]);
    }
}

// ---------------- workspace layout (bytes) ----------------
constexpr size_t SE_OFF = 0;                       // fp32 8192x512   (16 MB)
constexpr size_t SQB_OFF = 16777216;               // bf16 8192x512: squeeze out, later ctx
constexpr size_t SEB_OFF = 25165824;               // bf16 8192x512: se bf16; later pos2
constexpr size_t Q_OFF = 33554432;                 // bf16 8192x512 (aliases Xb)
constexpr size_t K_OFF = 41943040;                 // bf16 8192x512 (h first half)
constexpr size_t V_OFF = 50331648;                 // bf16 8192x512 (h second half)
constexpr size_t XB_OFF = Q_OFF;                   // bf16 X copy, dead before q written
constexpr size_t H_OFF = K_OFF;                    // bf16 8192x1024, dead before k/v written
constexpr size_t POS2_OFF = SEB_OFF;               // float4 x 8192 = 128 KB, after seb dead
constexpr size_t WTE_OFF = 58720256;               // bf16 1024x512
constexpr size_t WTS_OFF = WTE_OFF + 1048576;      // bf16 512x1024
constexpr size_t WTQKV_OFF = WTS_OFF + 1048576;    // bf16 1536x512
// end = 62,390,272 bytes

extern "C" void kernel_launch(void* const* d_in, const int* in_sizes, int n_in,
                              void* d_out, int out_size, void* d_ws, size_t ws_size,
                              hipStream_t stream) {
  const float* X = (const float*)d_in[0];
  const float* pos = (const float*)d_in[1];
  const float* W_expand = (const float*)d_in[2];
  const float* b_expand = (const float*)d_in[3];
  const float* W_squeeze = (const float*)d_in[4];
  const float* b_squeeze = (const float*)d_in[5];
  const float* gamma = (const float*)d_in[6];
  const float* beta = (const float*)d_in[7];
  const float* Wq = (const float*)d_in[8];
  const float* bq = (const float*)d_in[9];
  const float* Wk = (const float*)d_in[10];
  const float* bk = (const float*)d_in[11];
  const float* Wv = (const float*)d_in[12];
  const float* bv = (const float*)d_in[13];
  const float* alphap = (const float*)d_in[14];

  char* ws = (char*)d_ws;
  float* se = (float*)(ws + SE_OFF);
  bf16_t* sqb = (bf16_t*)(ws + SQB_OFF);
  bf16_t* ctxb = (bf16_t*)(ws + SQB_OFF);  // reuses sqb slot (sq dead after LN)
  bf16_t* seb = (bf16_t*)(ws + SEB_OFF);
  float* pos2 = (float*)(ws + POS2_OFF);   // written after seb is dead
  bf16_t* qb = (bf16_t*)(ws + Q_OFF);
  bf16_t* kb = (bf16_t*)(ws + K_OFF);
  bf16_t* vb = (bf16_t*)(ws + V_OFF);
  bf16_t* xbb = (bf16_t*)(ws + XB_OFF);
  bf16_t* hb = (bf16_t*)(ws + H_OFF);
  bf16_t* wtE = (bf16_t*)(ws + WTE_OFF);
  bf16_t* wtS = (bf16_t*)(ws + WTS_OFF);
  bf16_t* wtQKV = (bf16_t*)(ws + WTQKV_OFF);

  // fused prep: X->bf16 + all weight transposes (one launch)
  prep_k<<<3840, 256, 0, stream>>>(X, xbb, W_expand, wtE, W_squeeze, wtS,
                                   Wq, Wk, Wv, wtQKV);

  // h = relu(X @ We + be)            [8192,1024] bf16
  gemm128_k<0><<<dim3(1024 / 128, Mrows / 128), 256, 0, stream>>>(
      xbb, wtE, b_expand, nullptr, nullptr, hb, nullptr, nullptr, 1024, 512);
  // sq = h @ Ws + bs                 [8192,512] bf16
  gemm128_k<1><<<dim3(512 / 128, Mrows / 128), 256, 0, stream>>>(
      hb, wtS, b_squeeze, nullptr, nullptr, sqb, nullptr, nullptr, 512, 1024);
  // se = LN(X + sq)  (fp32 + bf16 copy)
  ln_k<1><<<Mrows / 4, 256, 0, stream>>>(X, sqb, gamma, beta, se, seb);
  // q,k,v = se @ [Wq|Wk|Wv] + b      scattered bf16
  gemm128_k<2><<<dim3(1536 / 128, Mrows / 128), 256, 0, stream>>>(
      seb, wtQKV, bq, bk, bv, qb, kb, vb, 1536, 512);
  // pack positions with folded alpha (seb now dead; pos2 aliases it)
  pospack_k<<<Mrows / 256, 256, 0, stream>>>(pos, alphap, pos2);
  // ctx = attention(q,k,v,pos2)      [8192,512] bf16 (reuses sqb slot)
  attn_k<<<dim3(Sc / 64, Hc, Bc), 256, 0, stream>>>(qb, kb, vb, pos2, alphap, ctxb);
  // out = LN(se + ctx)
  ln_k<0><<<Mrows / 4, 256, 0, stream>>>(se, ctxb, gamma, beta, (float*)d_out, nullptr);

  (void)in_sizes; (void)n_in; (void)out_size; (void)ws_size;
}

// Round 6
// 235.674 us; speedup vs baseline: 1.5095x; 1.0329x over previous
//
#include <hip/hip_runtime.h>

typedef __bf16 bf16_t;
typedef __attribute__((ext_vector_type(8))) __bf16 bf16x8;
typedef __attribute__((ext_vector_type(4))) __bf16 bf16x4;
typedef __attribute__((ext_vector_type(4))) float f32x4;
typedef __attribute__((ext_vector_type(16))) float f32x16;

constexpr int Bc = 4, Sc = 2048, Dc = 512, Hc = 4, HDc = 128;
constexpr int Mrows = Bc * Sc;  // 8192

// Contract (empirically proven m97/r1-r4): source address = per-lane,
// LDS dest = wave-uniform base + lane*16. Keep sources base+lane*16-contiguous
// or plain row-strided; NEVER xor-swizzled, NEVER wave-uniform.
__device__ inline void gl2lds(const void* g, void* l) {
  __builtin_amdgcn_global_load_lds(
      (__attribute__((address_space(1))) void*)g,
      (__attribute__((address_space(3))) void*)l, 16, 0, 0);
}

// ---------- fused prep: X->bf16 cast (blocks 0..2047) + 5 weight transposes ----------
__global__ __launch_bounds__(256) void prep_k(
    const float* __restrict__ X, bf16_t* __restrict__ xb,
    const float* __restrict__ We, bf16_t* __restrict__ wtE,
    const float* __restrict__ Ws, bf16_t* __restrict__ wtS,
    const float* __restrict__ Wq, const float* __restrict__ Wk,
    const float* __restrict__ Wv, bf16_t* __restrict__ wtQKV) {
  const int bid = blockIdx.x;
  if (bid < 2048) {
    const long i = ((long)bid * 256 + threadIdx.x) * 8;
    const float4 a = *(const float4*)(X + i);
    const float4 c = *(const float4*)(X + i + 4);
    bf16x8 o;
    o[0] = (bf16_t)a.x; o[1] = (bf16_t)a.y; o[2] = (bf16_t)a.z; o[3] = (bf16_t)a.w;
    o[4] = (bf16_t)c.x; o[5] = (bf16_t)c.y; o[6] = (bf16_t)c.z; o[7] = (bf16_t)c.w;
    *(bf16x8*)(xb + i) = o;
    return;
  }
  __shared__ float tile[32][33];
  const float* src; bf16_t* dst; int K, N, local;
  if (bid < 2560)      { src = We; dst = wtE; K = 512;  N = 1024; local = bid - 2048; }
  else if (bid < 3072) { src = Ws; dst = wtS; K = 1024; N = 512;  local = bid - 2560; }
  else if (bid < 3328) { src = Wq; dst = wtQKV;          K = 512; N = 512; local = bid - 3072; }
  else if (bid < 3584) { src = Wk; dst = wtQKV + 262144; K = 512; N = 512; local = bid - 3328; }
  else                 { src = Wv; dst = wtQKV + 524288; K = 512; N = 512; local = bid - 3584; }
  const int nb = N / 32;
  const int n0 = (local % nb) * 32, k0 = (local / nb) * 32;
  const int tx = threadIdx.x & 31, ty = threadIdx.x >> 5;
#pragma unroll
  for (int i = 0; i < 4; i++)
    tile[ty + i * 8][tx] = src[(long)(k0 + ty + i * 8) * N + n0 + tx];
  __syncthreads();
#pragma unroll
  for (int i = 0; i < 4; i++)
    dst[(long)(n0 + ty + i * 8) * K + k0 + tx] = (bf16_t)tile[tx][ty + i * 8];
}

// ---------- pack positions: pos2[s] = (x, y, z, -alpha*log2e*|p|^2) ----------
__global__ __launch_bounds__(256) void pospack_k(const float* __restrict__ pos,
                                                 const float* __restrict__ alphap,
                                                 float* __restrict__ pos2) {
  const float aL = alphap[0] * 1.4426950408889634f;
  const int i = blockIdx.x * 256 + threadIdx.x;
  const float x = pos[(long)i * 3], y = pos[(long)i * 3 + 1], z = pos[(long)i * 3 + 2];
  float4 o; o.x = x; o.y = y; o.z = z; o.w = -aL * (x * x + y * y + z * z);
  *(float4*)(pos2 + (long)i * 4) = o;
}

// ---------- 128xTN MFMA GEMM, BK=64, linear (r4-proven) gl2lds staging ----------
// OMODE: 0 = relu+bias -> bf16 ; 1 = bias -> bf16 ; 2 = qkv scatter bf16
template <int OMODE, int TN>
__global__ __launch_bounds__(256, 3) void gemm128_k(
    const bf16_t* __restrict__ A, const bf16_t* __restrict__ Bt,
    const float* __restrict__ bias0, const float* __restrict__ bias1,
    const float* __restrict__ bias2, void* __restrict__ out0,
    void* __restrict__ out1, void* __restrict__ out2, int N, int K) {
  __shared__ bf16_t As[128 * 64];  // [row][64], unpadded linear
  __shared__ bf16_t Bs[TN * 64];
  constexpr int MT = (TN == 128) ? 4 : 2;
  constexpr int BI = (TN == 128) ? 4 : 2;
  constexpr int MW = (TN == 128) ? 64 : 32;
  const int t = threadIdx.x;
  const int n0 = blockIdx.x * TN, m0 = blockIdx.y * 128;
  const int lane = t & 63, wave = t >> 6;
  const int quad = lane >> 4, ln = lane & 15;
  const int wm = (TN == 128) ? (wave >> 1) : wave;
  const int wn = (TN == 128) ? (wave & 1) : 0;
  const int l8 = lane >> 3, g = lane & 7;
  const bf16_t* aseg = A + (long)(m0 + wave * 32 + l8) * K + g * 8;
  const bf16_t* bseg = Bt + (long)(n0 + wave * (BI * 8) + l8) * K + g * 8;
  bf16_t* asl = &As[(wave * 32) * 64];
  bf16_t* bsl = &Bs[(wave * BI * 8) * 64];
  f32x4 acc[MT][4] = {};
  for (int k0 = 0; k0 < K; k0 += 64) {
#pragma unroll
    for (int i = 0; i < 4; i++)
      gl2lds(aseg + (long)i * 8 * K + k0, asl + i * 8 * 64);
#pragma unroll
    for (int i = 0; i < BI; i++)
      gl2lds(bseg + (long)i * 8 * K + k0, bsl + i * 8 * 64);
    __syncthreads();
#pragma unroll
    for (int kc = 0; kc < 2; kc++) {
      bf16x8 af[MT], bfr[4];
#pragma unroll
      for (int mt = 0; mt < MT; mt++)
        af[mt] = *(const bf16x8*)&As[(wm * MW + mt * 16 + ln) * 64 + kc * 32 + quad * 8];
#pragma unroll
      for (int nt = 0; nt < 4; nt++)
        bfr[nt] = *(const bf16x8*)&Bs[(wn * 64 + nt * 16 + ln) * 64 + kc * 32 + quad * 8];
#pragma unroll
      for (int mt = 0; mt < MT; mt++)
#pragma unroll
        for (int nt = 0; nt < 4; nt++)
          acc[mt][nt] = __builtin_amdgcn_mfma_f32_16x16x32_bf16(af[mt], bfr[nt],
                                                                acc[mt][nt], 0, 0, 0);
    }
    __syncthreads();
  }
#pragma unroll
  for (int nt = 0; nt < 4; nt++) {
    const int gcol = n0 + wn * 64 + nt * 16 + ln;
    if constexpr (OMODE == 0 || OMODE == 1) {
      const float bv = bias0[gcol];
      bf16_t* o = (bf16_t*)out0;
#pragma unroll
      for (int mt = 0; mt < MT; mt++)
#pragma unroll
        for (int r = 0; r < 4; r++) {
          const int grow = m0 + wm * MW + mt * 16 + quad * 4 + r;
          float vv = acc[mt][nt][r] + bv;
          if constexpr (OMODE == 0) vv = vv > 0.f ? vv : 0.f;
          o[(long)grow * N + gcol] = (bf16_t)vv;
        }
    } else {
      const int which = gcol >> 9, n = gcol & 511;
      const int hh = n >> 7, hd = n & 127;
      const float bv = (which == 0 ? bias0 : which == 1 ? bias1 : bias2)[n];
      bf16_t* o = (bf16_t*)(which == 0 ? out0 : which == 1 ? out1 : out2);
#pragma unroll
      for (int mt = 0; mt < MT; mt++)
#pragma unroll
        for (int r = 0; r < 4; r++) {
          const int grow = m0 + wm * MW + mt * 16 + quad * 4 + r;
          const int b = grow >> 11, s = grow & 2047;
          const float vv = acc[mt][nt][r] + bv;
          long idx;
          if (which == 0) {  // q: [b,h,s,128] row-major
            idx = ((long)((b * Hc + hh) * Sc + s)) * HDc + hd;
          } else if (which == 1) {  // k frag-native: [b,h,t][kh][c][lane][8]
            const int tt = s >> 6, kh = (s >> 5) & 1, key = s & 31;
            const int c = hd >> 4, lk = key + 32 * ((hd >> 3) & 1), j = hd & 7;
            idx = ((((long)((b * Hc + hh) * 32 + tt) * 2 + kh) * 8 + c) * 64 + lk) * 8 + j;
          } else {  // v frag-native: [b,h,t][ht][kc][lane][8]
            const int tt = s >> 6, ht2 = hd >> 5, kc = (s & 63) >> 4;
            const int lk = (hd & 31) + 32 * ((s >> 3) & 1), j = s & 7;
            idx = ((((long)((b * Hc + hh) * 32 + tt) * 4 + ht2) * 4 + kc) * 64 + lk) * 8 + j;
          }
          o[idx] = (bf16_t)vv;
        }
    }
  }
}

// ---------- LayerNorm(xa_fp32 + xb_bf16): one wave per row of 512 ----------
template <int DUAL>
__global__ __launch_bounds__(256) void ln_k(const float* __restrict__ xa,
                                            const bf16_t* __restrict__ xb,
                                            const float* __restrict__ gamma,
                                            const float* __restrict__ beta,
                                            float* __restrict__ out,
                                            bf16_t* __restrict__ outb) {
  const int wave = threadIdx.x >> 6, lane = threadIdx.x & 63;
  const long row = (long)blockIdx.x * 4 + wave;
  const float* a = xa + row * Dc;
  const bf16_t* bp = xb + row * Dc;
  float vv[8];
  float s = 0.f, s2 = 0.f;
#pragma unroll
  for (int i = 0; i < 2; i++) {
    const float4 va = *(const float4*)(a + lane * 4 + i * 256);
    const bf16x4 vb = *(const bf16x4*)(bp + lane * 4 + i * 256);
    const float xs[4] = {va.x, va.y, va.z, va.w};
#pragma unroll
    for (int j = 0; j < 4; j++) {
      const float x = xs[j] + (float)vb[j];
      vv[i * 4 + j] = x;
      s += x;
      s2 += x * x;
    }
  }
#pragma unroll
  for (int off = 1; off < 64; off <<= 1) {
    s += __shfl_xor(s, off, 64);
    s2 += __shfl_xor(s2, off, 64);
  }
  const float mu = s * (1.f / Dc);
  const float var = s2 * (1.f / Dc) - mu * mu;
  const float rstd = rsqrtf(var + 1e-5f);
#pragma unroll
  for (int i = 0; i < 2; i++)
#pragma unroll
    for (int j = 0; j < 4; j++) {
      const int col = lane * 4 + i * 256 + j;
      const float o = (vv[i * 4 + j] - mu) * rstd * gamma[col] + beta[col];
      out[row * Dc + col] = o;
      if constexpr (DUAL) outb[row * Dc + col] = (bf16_t)o;
    }
}

// ---------- flash attention: S^T = K Q^T, 32x32 MFMA, fp32 bias, frag-native ----
// q: [b,h,s,128]; Kg,Vg frag-native tiled; pos2 (x,y,z,-aL|p|^2); ctx bf16 [b,s,D]
__global__ __launch_bounds__(256, 2) void attn_k(const bf16_t* __restrict__ q,
                                                 const bf16_t* __restrict__ Kg,
                                                 const bf16_t* __restrict__ Vg,
                                                 const float* __restrict__ pos2,
                                                 const float* __restrict__ alphap,
                                                 bf16_t* __restrict__ ctx) {
  __shared__ bf16_t Ks[2][8192];   // [kh][c][lane][8] frag-native
  __shared__ bf16_t Vts[2][8192];  // [ht][kc][lane][8]
  __shared__ float pk4[2][64][4];  // key positions (x,y,z,-aL|p|^2)
  __shared__ bf16_t Ps[4][1024];   // per-wave P^T B-frags [c2][lane][8]
  __shared__ float RsD[4][32];
  const int t = threadIdx.x;
  const int qt = blockIdx.x, h = blockIdx.y, b = blockIdx.z;
  const int q0 = qt * 64;
  const int wave = t >> 6, lane = t & 63;
  const int l31 = lane & 31, hb = lane >> 5;
  const int rh = wave & 1, kh = wave >> 1;
  const float l2e = 1.4426950408889634f;
  const float scale_l2 = l2e * 0.08838834764831845f;  // log2e/sqrt(128)
  const float aL = alphap[0] * l2e;

  // Q fragments (B-operand layout == A layout): q-row = q0+rh*32+l31 (lane-fixed)
  bf16x8 qf[8];
  const long qrow = (long)((b * Hc + h) * Sc + q0 + rh * 32 + l31);
#pragma unroll
  for (int c = 0; c < 8; c++)
    qf[c] = *(const bf16x8*)(q + qrow * HDc + c * 16 + hb * 8);
  // q position, prescaled by 2*aL (the -aL|pq|^2 row-constant cancels in softmax)
  float pqx, pqy, pqz;
  {
    const float4 p = *(const float4*)(pos2 + (long)(b * Sc + q0 + rh * 32 + l31) * 4);
    pqx = 2.f * aL * p.x; pqy = 2.f * aL * p.y; pqz = 2.f * aL * p.z;
  }

  // staging: all sources are base + lane*16B (contiguous per-lane)
  const bf16_t* ktile = Kg + (long)((b * Hc + h) * 32) * 8192 + lane * 8;
  const bf16_t* vtile = Vg + (long)((b * Hc + h) * 32) * 8192 + lane * 8;
  const float* pcur = pos2 + (long)b * Sc * 4 + lane * 4;
  auto stage = [&](int buf) {
#pragma unroll
    for (int i = 0; i < 4; i++)
      gl2lds(ktile + (wave * 4 + i) * 512, &Ks[buf][(wave * 4 + i) * 512]);
#pragma unroll
    for (int i = 0; i < 4; i++)
      gl2lds(vtile + (wave * 4 + i) * 512, &Vts[buf][(wave * 4 + i) * 512]);
    if (wave == 0) gl2lds(pcur, &pk4[buf][0][0]);
  };
  stage(0);
  ktile += 8192; vtile += 8192; pcur += 256;

  float rsl = 0.f;
  f32x16 accT[4] = {};
  // P^T B-frag write base: element (key=kp, q=l31) -> c2*512 + (l31+32*((kp>>3)&1))*8 + (kp&7)
  bf16_t* pwbase = &Ps[wave][l31 * 8 + 4 * hb];

  for (int kt = 0; kt < Sc / 64; kt++) {
    const int cur = kt & 1;
    __syncthreads();  // buf[cur] staged; prev readers done
    if (kt < Sc / 64 - 1) {
      stage(1 - cur);
      ktile += 8192; vtile += 8192; pcur += 256;
    }
    // S^T = K Q^T : rows = keys (kh half), cols = q
    f32x16 sacc = {};
#pragma unroll
    for (int c = 0; c < 8; c++) {
      const bf16x8 kf = *(const bf16x8*)&Ks[cur][(kh * 8 + c) * 512 + lane * 8];
      sacc = __builtin_amdgcn_mfma_f32_32x32x16_bf16(kf, qf[c], sacc, 0, 0, 0);
    }
    // p = 2^(s*scale + pk.w + pq2aL . pk); C row = key kp = (r&3)+8*(r>>2)+4*hb, col = q = l31
#pragma unroll
    for (int g2 = 0; g2 < 4; g2++)
#pragma unroll
      for (int r0 = 0; r0 < 4; r0++) {
        const int kp = r0 + 4 * hb + 8 * g2;
        const float4 pv = *(const float4*)&pk4[cur][kh * 32 + kp][0];  // 32-lane broadcast
        const float bias = __builtin_fmaf(pqx, pv.x,
                           __builtin_fmaf(pqy, pv.y,
                           __builtin_fmaf(pqz, pv.z, pv.w)));
        const float p = __builtin_amdgcn_exp2f(
            __builtin_fmaf(sacc[g2 * 4 + r0], scale_l2, bias));
        rsl += p;
        pwbase[(g2 >> 1) * 512 + (g2 & 1) * 256 + r0] = (bf16_t)p;  // wave-private
      }
    // O^T += V^T P^T : A = Vts frags, B = Ps
    const bf16x8 pf0 = *(const bf16x8*)&Ps[wave][lane * 8];
    const bf16x8 pf1 = *(const bf16x8*)&Ps[wave][512 + lane * 8];
#pragma unroll
    for (int ht = 0; ht < 4; ht++) {
      const bf16x8 v0 = *(const bf16x8*)&Vts[cur][(ht * 4 + kh * 2 + 0) * 512 + lane * 8];
      accT[ht] = __builtin_amdgcn_mfma_f32_32x32x16_bf16(v0, pf0, accT[ht], 0, 0, 0);
      const bf16x8 v1 = *(const bf16x8*)&Vts[cur][(ht * 4 + kh * 2 + 1) * 512 + lane * 8];
      accT[ht] = __builtin_amdgcn_mfma_f32_32x32x16_bf16(v1, pf1, accT[ht], 0, 0, 0);
    }
  }
  __syncthreads();  // all LDS reads done; Ks pool reusable

  // denominator for q = l31: lane sums its 16 key-rows, partner hb has the rest
  rsl += __shfl_xor(rsl, 32, 64);
  if (hb == 0) RsD[wave][l31] = rsl;
  // kh=1 waves dump O^T partial to LDS (reuse Ks pool: [hd128][q64] fp32 = 32KB)
  float* Oc = (float*)&Ks[0][0];
  if (kh == 1) {
#pragma unroll
    for (int ht = 0; ht < 4; ht++)
#pragma unroll
      for (int r = 0; r < 16; r++) {
        const int hdp = (r & 3) + 8 * (r >> 2) + 4 * hb;
        Oc[(ht * 32 + hdp) * 64 + rh * 32 + l31] = accT[ht][r];
      }
  }
  __syncthreads();
  if (kh == 0) {
    const float rinv = 1.f / (RsD[wave][l31] + RsD[wave + 2][l31]);
    const long orow = (long)(b * Sc + q0 + rh * 32 + l31);
#pragma unroll
    for (int ht = 0; ht < 4; ht++)
#pragma unroll
      for (int g2 = 0; g2 < 4; g2++) {
        bf16x4 ov;
#pragma unroll
        for (int r0 = 0; r0 < 4; r0++) {
          const int hdp = r0 + 8 * g2 + 4 * hb;
          ov[r0] = (bf16_t)((accT[ht][g2 * 4 + r0] +
                             Oc[(ht * 32 + hdp) * 64 + rh * 32 + l31]) * rinv);
        }
        *(bf16x4*)(ctx + orow * Dc + h * HDc + ht * 32 + 8 * g2 + 4 * hb) = ov;
      }
  }
}

// ---------------- workspace layout (bytes) ----------------
constexpr size_t SE_OFF = 0;                       // fp32 8192x512   (16 MB)
constexpr size_t SQB_OFF = 16777216;               // bf16 8192x512: squeeze out, later ctx
constexpr size_t SEB_OFF = 25165824;               // bf16 8192x512: se bf16; later pos2
constexpr size_t Q_OFF = 33554432;                 // bf16 8192x512 (aliases Xb)
constexpr size_t K_OFF = 41943040;                 // bf16 tiled 8 MB (h first half)
constexpr size_t V_OFF = 50331648;                 // bf16 tiled 8 MB (h second half)
constexpr size_t XB_OFF = Q_OFF;                   // bf16 X copy, dead before q written
constexpr size_t H_OFF = K_OFF;                    // bf16 8192x1024, dead before k/v written
constexpr size_t POS2_OFF = SEB_OFF;               // float4 x 8192 = 128 KB, after seb dead
constexpr size_t WTE_OFF = 58720256;               // bf16 1024x512
constexpr size_t WTS_OFF = WTE_OFF + 1048576;      // bf16 512x1024
constexpr size_t WTQKV_OFF = WTS_OFF + 1048576;    // bf16 1536x512
// end = 62,390,272 bytes

extern "C" void kernel_launch(void* const* d_in, const int* in_sizes, int n_in,
                              void* d_out, int out_size, void* d_ws, size_t ws_size,
                              hipStream_t stream) {
  const float* X = (const float*)d_in[0];
  const float* pos = (const float*)d_in[1];
  const float* W_expand = (const float*)d_in[2];
  const float* b_expand = (const float*)d_in[3];
  const float* W_squeeze = (const float*)d_in[4];
  const float* b_squeeze = (const float*)d_in[5];
  const float* gamma = (const float*)d_in[6];
  const float* beta = (const float*)d_in[7];
  const float* Wq = (const float*)d_in[8];
  const float* bq = (const float*)d_in[9];
  const float* Wk = (const float*)d_in[10];
  const float* bk = (const float*)d_in[11];
  const float* Wv = (const float*)d_in[12];
  const float* bv = (const float*)d_in[13];
  const float* alphap = (const float*)d_in[14];

  char* ws = (char*)d_ws;
  float* se = (float*)(ws + SE_OFF);
  bf16_t* sqb = (bf16_t*)(ws + SQB_OFF);
  bf16_t* ctxb = (bf16_t*)(ws + SQB_OFF);  // reuses sqb slot (sq dead after LN)
  bf16_t* seb = (bf16_t*)(ws + SEB_OFF);
  float* pos2 = (float*)(ws + POS2_OFF);   // written after seb is dead
  bf16_t* qb = (bf16_t*)(ws + Q_OFF);
  bf16_t* kb = (bf16_t*)(ws + K_OFF);
  bf16_t* vb = (bf16_t*)(ws + V_OFF);
  bf16_t* xbb = (bf16_t*)(ws + XB_OFF);
  bf16_t* hb = (bf16_t*)(ws + H_OFF);
  bf16_t* wtE = (bf16_t*)(ws + WTE_OFF);
  bf16_t* wtS = (bf16_t*)(ws + WTS_OFF);
  bf16_t* wtQKV = (bf16_t*)(ws + WTQKV_OFF);

  // fused prep: X->bf16 + all weight transposes
  prep_k<<<3840, 256, 0, stream>>>(X, xbb, W_expand, wtE, W_squeeze, wtS,
                                   Wq, Wk, Wv, wtQKV);
  // h = relu(X @ We + be)            [8192,1024] bf16
  gemm128_k<0, 128><<<dim3(1024 / 128, Mrows / 128), 256, 0, stream>>>(
      xbb, wtE, b_expand, nullptr, nullptr, hb, nullptr, nullptr, 1024, 512);
  // sq = h @ Ws + bs                 [8192,512] bf16 (TN=64: 512 blocks)
  gemm128_k<1, 64><<<dim3(512 / 64, Mrows / 128), 256, 0, stream>>>(
      hb, wtS, b_squeeze, nullptr, nullptr, sqb, nullptr, nullptr, 512, 1024);
  // se = LN(X + sq)  (fp32 + bf16 copy)
  ln_k<1><<<Mrows / 4, 256, 0, stream>>>(X, sqb, gamma, beta, se, seb);
  // q,k,v = se @ [Wq|Wk|Wv] + b      q row-major; k,v frag-native tiled
  gemm128_k<2, 128><<<dim3(1536 / 128, Mrows / 128), 256, 0, stream>>>(
      seb, wtQKV, bq, bk, bv, qb, kb, vb, 1536, 512);
  // pack positions (seb dead -> pos2 aliases it)
  pospack_k<<<Mrows / 256, 256, 0, stream>>>(pos, alphap, pos2);
  // ctx = attention                  [8192,512] bf16
  attn_k<<<dim3(Sc / 64, Hc, Bc), 256, 0, stream>>>(qb, kb, vb, pos2, alphap, ctxb);
  // out = LN(se + ctx)
  ln_k<0><<<Mrows / 4, 256, 0, stream>>>(se, ctxb, gamma, beta, (float*)d_out, nullptr);

  (void)in_sizes; (void)n_in; (void)out_size; (void)ws_size;
}

// Round 7
// 233.549 us; speedup vs baseline: 1.5232x; 1.0091x over previous
//
#include <hip/hip_runtime.h>

typedef __bf16 bf16_t;
typedef __attribute__((ext_vector_type(8))) __bf16 bf16x8;
typedef __attribute__((ext_vector_type(4))) __bf16 bf16x4;
typedef __attribute__((ext_vector_type(4))) float f32x4;
typedef __attribute__((ext_vector_type(16))) float f32x16;

constexpr int Bc = 4, Sc = 2048, Dc = 512, Hc = 4, HDc = 128;
constexpr int Mrows = Bc * Sc;  // 8192

// gl2lds contract (r5/r6 lesson): source address MUST be per-lane (any per-lane
// permutation is fine — the DMA is a gather); LDS dest is wave-uniform base +
// lane*16. Wave-uniform sources silently replicate one 16B chunk (r5 bug).
__device__ inline void gl2lds(const void* g, void* l) {
  __builtin_amdgcn_global_load_lds(
      (__attribute__((address_space(1))) void*)g,
      (__attribute__((address_space(3))) void*)l, 16, 0, 0);
}

// ---------- fused prep: X->bf16 cast (blocks 0..2047) + 5 weight transposes ----------
__global__ __launch_bounds__(256) void prep_k(
    const float* __restrict__ X, bf16_t* __restrict__ xb,
    const float* __restrict__ We, bf16_t* __restrict__ wtE,
    const float* __restrict__ Ws, bf16_t* __restrict__ wtS,
    const float* __restrict__ Wq, const float* __restrict__ Wk,
    const float* __restrict__ Wv, bf16_t* __restrict__ wtQKV) {
  const int bid = blockIdx.x;
  if (bid < 2048) {
    const long i = ((long)bid * 256 + threadIdx.x) * 8;
    const float4 a = *(const float4*)(X + i);
    const float4 c = *(const float4*)(X + i + 4);
    bf16x8 o;
    o[0] = (bf16_t)a.x; o[1] = (bf16_t)a.y; o[2] = (bf16_t)a.z; o[3] = (bf16_t)a.w;
    o[4] = (bf16_t)c.x; o[5] = (bf16_t)c.y; o[6] = (bf16_t)c.z; o[7] = (bf16_t)c.w;
    *(bf16x8*)(xb + i) = o;
    return;
  }
  __shared__ float tile[32][33];
  const float* src; bf16_t* dst; int K, N, local;
  if (bid < 2560)      { src = We; dst = wtE; K = 512;  N = 1024; local = bid - 2048; }
  else if (bid < 3072) { src = Ws; dst = wtS; K = 1024; N = 512;  local = bid - 2560; }
  else if (bid < 3328) { src = Wq; dst = wtQKV;          K = 512; N = 512; local = bid - 3072; }
  else if (bid < 3584) { src = Wk; dst = wtQKV + 262144; K = 512; N = 512; local = bid - 3328; }
  else                 { src = Wv; dst = wtQKV + 524288; K = 512; N = 512; local = bid - 3584; }
  const int nb = N / 32;
  const int n0 = (local % nb) * 32, k0 = (local / nb) * 32;
  const int tx = threadIdx.x & 31, ty = threadIdx.x >> 5;
#pragma unroll
  for (int i = 0; i < 4; i++)
    tile[ty + i * 8][tx] = src[(long)(k0 + ty + i * 8) * N + n0 + tx];
  __syncthreads();
#pragma unroll
  for (int i = 0; i < 4; i++)
    dst[(long)(n0 + ty + i * 8) * K + k0 + tx] = (bf16_t)tile[tx][ty + i * 8];
}

// ---------- pack positions: pos2[s] = (x, y, z, -alpha*log2e*|p|^2) ----------
__global__ __launch_bounds__(256) void pospack_k(const float* __restrict__ pos,
                                                 const float* __restrict__ alphap,
                                                 float* __restrict__ pos2) {
  const float aL = alphap[0] * 1.4426950408889634f;
  const int i = blockIdx.x * 256 + threadIdx.x;
  const float x = pos[(long)i * 3], y = pos[(long)i * 3 + 1], z = pos[(long)i * 3 + 2];
  float4 o; o.x = x; o.y = y; o.z = z; o.w = -aL * (x * x + y * y + z * z);
  *(float4*)(pos2 + (long)i * 4) = o;
}

// ---------- 128xTN MFMA GEMM, BK=64, dbuf prefetch + XOR-swizzled LDS ----------
// LDS[row][c] holds global[row][c ^ (row&7)] (8-elem col groups). Staged with
// per-lane source col-group g^l8; readers XOR-unswizzle -> conflict-free b128.
// OMODE: 0 = relu+bias -> bf16 ; 1 = bias -> bf16 ; 2 = qkv scatter bf16
template <int OMODE, int TN>
__global__ __launch_bounds__(256, (TN == 128) ? 2 : 3) void gemm128_k(
    const bf16_t* __restrict__ A, const bf16_t* __restrict__ Bt,
    const float* __restrict__ bias0, const float* __restrict__ bias1,
    const float* __restrict__ bias2, void* __restrict__ out0,
    void* __restrict__ out1, void* __restrict__ out2, int N, int K) {
  __shared__ bf16_t As[2][128 * 64];
  __shared__ bf16_t Bs[2][TN * 64];
  constexpr int MT = (TN == 128) ? 4 : 2;
  constexpr int BI = (TN == 128) ? 4 : 2;
  constexpr int MW = (TN == 128) ? 64 : 32;
  const int t = threadIdx.x;
  const int n0 = blockIdx.x * TN, m0 = blockIdx.y * 128;
  const int lane = t & 63, wave = t >> 6;
  const int quad = lane >> 4, ln = lane & 15;
  const int wm = (TN == 128) ? (wave >> 1) : wave;
  const int wn = (TN == 128) ? (wave & 1) : 0;
  const int l8 = lane >> 3, g = lane & 7;
  // per-lane staging sources; col-group XOR-swizzled by row-within-8 (= l8)
  const bf16_t* aseg = A + (long)(m0 + wave * 32 + l8) * K + (g ^ l8) * 8;
  const bf16_t* bseg = Bt + (long)(n0 + wave * (BI * 8) + l8) * K + (g ^ l8) * 8;
  auto stage = [&](int buf, int k0) {
#pragma unroll
    for (int i = 0; i < 4; i++)
      gl2lds(aseg + (long)i * 8 * K + k0, &As[buf][(wave * 32 + i * 8) * 64]);
#pragma unroll
    for (int i = 0; i < BI; i++)
      gl2lds(bseg + (long)i * 8 * K + k0, &Bs[buf][(wave * BI * 8 + i * 8) * 64]);
  };
  f32x4 acc[MT][4] = {};
  stage(0, 0);
  const int niter = K / 64;
  for (int it = 0; it < niter; it++) {
    const int cur = it & 1;
    __syncthreads();  // buf[cur] staged (prefetch had a full iter); prev readers done
    if (it + 1 < niter) stage(1 - cur, (it + 1) * 64);
#pragma unroll
    for (int kc = 0; kc < 2; kc++) {
      bf16x8 af[MT], bfr[4];
#pragma unroll
      for (int mt = 0; mt < MT; mt++)
        af[mt] = *(const bf16x8*)&As[cur][(wm * MW + mt * 16 + ln) * 64 +
                                          (((kc * 4 + quad) ^ (ln & 7)) * 8)];
#pragma unroll
      for (int nt = 0; nt < 4; nt++)
        bfr[nt] = *(const bf16x8*)&Bs[cur][(wn * 64 + nt * 16 + ln) * 64 +
                                           (((kc * 4 + quad) ^ (ln & 7)) * 8)];
#pragma unroll
      for (int mt = 0; mt < MT; mt++)
#pragma unroll
        for (int nt = 0; nt < 4; nt++)
          acc[mt][nt] = __builtin_amdgcn_mfma_f32_16x16x32_bf16(af[mt], bfr[nt],
                                                                acc[mt][nt], 0, 0, 0);
    }
  }
#pragma unroll
  for (int nt = 0; nt < 4; nt++) {
    const int gcol = n0 + wn * 64 + nt * 16 + ln;
    if constexpr (OMODE == 0 || OMODE == 1) {
      const float bv = bias0[gcol];
      bf16_t* o = (bf16_t*)out0;
#pragma unroll
      for (int mt = 0; mt < MT; mt++)
#pragma unroll
        for (int r = 0; r < 4; r++) {
          const int grow = m0 + wm * MW + mt * 16 + quad * 4 + r;
          float vv = acc[mt][nt][r] + bv;
          if constexpr (OMODE == 0) vv = vv > 0.f ? vv : 0.f;
          o[(long)grow * N + gcol] = (bf16_t)vv;
        }
    } else {
      const int which = gcol >> 9, n = gcol & 511;
      const int hh = n >> 7, hd = n & 127;
      const float bv = (which == 0 ? bias0 : which == 1 ? bias1 : bias2)[n];
      bf16_t* o = (bf16_t*)(which == 0 ? out0 : which == 1 ? out1 : out2);
#pragma unroll
      for (int mt = 0; mt < MT; mt++)
#pragma unroll
        for (int r = 0; r < 4; r++) {
          const int grow = m0 + wm * MW + mt * 16 + quad * 4 + r;
          const int b = grow >> 11, s = grow & 2047;
          const float vv = acc[mt][nt][r] + bv;
          long idx;
          if (which == 0) {  // q: [b,h,s,128] row-major
            idx = ((long)((b * Hc + hh) * Sc + s)) * HDc + hd;
          } else if (which == 1) {  // k frag-native: [b,h,t][kh][c][lane][8]
            const int tt = s >> 6, kh = (s >> 5) & 1, key = s & 31;
            const int c = hd >> 4, lk = key + 32 * ((hd >> 3) & 1), j = hd & 7;
            idx = ((((long)((b * Hc + hh) * 32 + tt) * 2 + kh) * 8 + c) * 64 + lk) * 8 + j;
          } else {  // v frag-native: [b,h,t][ht][kc][lane][8]
            const int tt = s >> 6, ht2 = hd >> 5, kc = (s & 63) >> 4;
            const int lk = (hd & 31) + 32 * ((s >> 3) & 1), j = s & 7;
            idx = ((((long)((b * Hc + hh) * 32 + tt) * 4 + ht2) * 4 + kc) * 64 + lk) * 8 + j;
          }
          o[idx] = (bf16_t)vv;
        }
    }
  }
}

// ---------- LayerNorm(xa_fp32 + xb_bf16): one wave per row of 512 ----------
template <int DUAL>
__global__ __launch_bounds__(256) void ln_k(const float* __restrict__ xa,
                                            const bf16_t* __restrict__ xb,
                                            const float* __restrict__ gamma,
                                            const float* __restrict__ beta,
                                            float* __restrict__ out,
                                            bf16_t* __restrict__ outb) {
  const int wave = threadIdx.x >> 6, lane = threadIdx.x & 63;
  const long row = (long)blockIdx.x * 4 + wave;
  const float* a = xa + row * Dc;
  const bf16_t* bp = xb + row * Dc;
  float vv[8];
  float s = 0.f, s2 = 0.f;
#pragma unroll
  for (int i = 0; i < 2; i++) {
    const float4 va = *(const float4*)(a + lane * 4 + i * 256);
    const bf16x4 vb = *(const bf16x4*)(bp + lane * 4 + i * 256);
    const float xs[4] = {va.x, va.y, va.z, va.w};
#pragma unroll
    for (int j = 0; j < 4; j++) {
      const float x = xs[j] + (float)vb[j];
      vv[i * 4 + j] = x;
      s += x;
      s2 += x * x;
    }
  }
#pragma unroll
  for (int off = 1; off < 64; off <<= 1) {
    s += __shfl_xor(s, off, 64);
    s2 += __shfl_xor(s2, off, 64);
  }
  const float mu = s * (1.f / Dc);
  const float var = s2 * (1.f / Dc) - mu * mu;
  const float rstd = rsqrtf(var + 1e-5f);
#pragma unroll
  for (int i = 0; i < 2; i++)
#pragma unroll
    for (int j = 0; j < 4; j++) {
      const int col = lane * 4 + i * 256 + j;
      const float o = (vv[i * 4 + j] - mu) * rstd * gamma[col] + beta[col];
      out[row * Dc + col] = o;
      if constexpr (DUAL) outb[row * Dc + col] = (bf16_t)o;
    }
}

// ---------- flash attention: S^T = K Q^T, 32x32 MFMA, fp32 bias, frag-native ----
// q: [b,h,s,128]; Kg,Vg frag-native tiled; pos2 (x,y,z,-aL|p|^2); ctx bf16 [b,s,D]
__global__ __launch_bounds__(256, 2) void attn_k(const bf16_t* __restrict__ q,
                                                 const bf16_t* __restrict__ Kg,
                                                 const bf16_t* __restrict__ Vg,
                                                 const float* __restrict__ pos2,
                                                 const float* __restrict__ alphap,
                                                 bf16_t* __restrict__ ctx) {
  __shared__ bf16_t Ks[2][8192];   // [kh][c][lane][8] frag-native
  __shared__ bf16_t Vts[2][8192];  // [ht][kc][lane][8]
  __shared__ float pk4[2][64][4];  // key positions (x,y,z,-aL|p|^2)
  __shared__ bf16_t Ps[4][1024];   // per-wave P^T B-frags [c2][lane][8]
  __shared__ float RsD[4][32];
  const int t = threadIdx.x;
  const int qt = blockIdx.x, h = blockIdx.y, b = blockIdx.z;
  const int q0 = qt * 64;
  const int wave = t >> 6, lane = t & 63;
  const int l31 = lane & 31, hb = lane >> 5;
  const int rh = wave & 1, kh = wave >> 1;
  const float l2e = 1.4426950408889634f;
  const float scale_l2 = l2e * 0.08838834764831845f;  // log2e/sqrt(128)
  const float aL = alphap[0] * l2e;

  // Q fragments (B-operand layout == A layout): q-row = q0+rh*32+l31 (lane-fixed)
  bf16x8 qf[8];
  const long qrow = (long)((b * Hc + h) * Sc + q0 + rh * 32 + l31);
#pragma unroll
  for (int c = 0; c < 8; c++)
    qf[c] = *(const bf16x8*)(q + qrow * HDc + c * 16 + hb * 8);
  // q position, prescaled by 2*aL (the -aL|pq|^2 row-constant cancels in softmax)
  float pqx, pqy, pqz;
  {
    const float4 p = *(const float4*)(pos2 + (long)(b * Sc + q0 + rh * 32 + l31) * 4);
    pqx = 2.f * aL * p.x; pqy = 2.f * aL * p.y; pqz = 2.f * aL * p.z;
  }

  // staging: all sources are base + lane*16B (contiguous per-lane)
  const bf16_t* ktile = Kg + (long)((b * Hc + h) * 32) * 8192 + lane * 8;
  const bf16_t* vtile = Vg + (long)((b * Hc + h) * 32) * 8192 + lane * 8;
  const float* pcur = pos2 + (long)b * Sc * 4 + lane * 4;
  auto stage = [&](int buf) {
#pragma unroll
    for (int i = 0; i < 4; i++)
      gl2lds(ktile + (wave * 4 + i) * 512, &Ks[buf][(wave * 4 + i) * 512]);
#pragma unroll
    for (int i = 0; i < 4; i++)
      gl2lds(vtile + (wave * 4 + i) * 512, &Vts[buf][(wave * 4 + i) * 512]);
    if (wave == 0) gl2lds(pcur, &pk4[buf][0][0]);
  };
  stage(0);
  ktile += 8192; vtile += 8192; pcur += 256;

  float rsl = 0.f;
  f32x16 accT[4] = {};
  // P^T B-frag write base: element (key=kp, q=l31) -> c2*512 + (l31+32*((kp>>3)&1))*8 + (kp&7)
  bf16_t* pwbase = &Ps[wave][l31 * 8 + 4 * hb];

  for (int kt = 0; kt < Sc / 64; kt++) {
    const int cur = kt & 1;
    __syncthreads();  // buf[cur] staged; prev readers done
    if (kt < Sc / 64 - 1) {
      stage(1 - cur);
      ktile += 8192; vtile += 8192; pcur += 256;
    }
    // S^T = K Q^T : rows = keys (kh half), cols = q
    f32x16 sacc = {};
#pragma unroll
    for (int c = 0; c < 8; c++) {
      const bf16x8 kf = *(const bf16x8*)&Ks[cur][(kh * 8 + c) * 512 + lane * 8];
      sacc = __builtin_amdgcn_mfma_f32_32x32x16_bf16(kf, qf[c], sacc, 0, 0, 0);
    }
    // p = 2^(s*scale + pk.w + pq2aL . pk); C row = key kp = (r&3)+8*(r>>2)+4*hb, col = q = l31
#pragma unroll
    for (int g2 = 0; g2 < 4; g2++)
#pragma unroll
      for (int r0 = 0; r0 < 4; r0++) {
        const int kp = r0 + 4 * hb + 8 * g2;
        const float4 pv = *(const float4*)&pk4[cur][kh * 32 + kp][0];  // 32-lane broadcast
        const float bias = __builtin_fmaf(pqx, pv.x,
                           __builtin_fmaf(pqy, pv.y,
                           __builtin_fmaf(pqz, pv.z, pv.w)));
        const float p = __builtin_amdgcn_exp2f(
            __builtin_fmaf(sacc[g2 * 4 + r0], scale_l2, bias));
        rsl += p;
        pwbase[(g2 >> 1) * 512 + (g2 & 1) * 256 + r0] = (bf16_t)p;  // wave-private
      }
    // O^T += V^T P^T : A = Vts frags, B = Ps
    const bf16x8 pf0 = *(const bf16x8*)&Ps[wave][lane * 8];
    const bf16x8 pf1 = *(const bf16x8*)&Ps[wave][512 + lane * 8];
#pragma unroll
    for (int ht = 0; ht < 4; ht++) {
      const bf16x8 v0 = *(const bf16x8*)&Vts[cur][(ht * 4 + kh * 2 + 0) * 512 + lane * 8];
      accT[ht] = __builtin_amdgcn_mfma_f32_32x32x16_bf16(v0, pf0, accT[ht], 0, 0, 0);
      const bf16x8 v1 = *(const bf16x8*)&Vts[cur][(ht * 4 + kh * 2 + 1) * 512 + lane * 8];
      accT[ht] = __builtin_amdgcn_mfma_f32_32x32x16_bf16(v1, pf1, accT[ht], 0, 0, 0);
    }
  }
  __syncthreads();  // all LDS reads done; Ks pool reusable

  // denominator for q = l31: lane sums its 16 key-rows, partner hb has the rest
  rsl += __shfl_xor(rsl, 32, 64);
  if (hb == 0) RsD[wave][l31] = rsl;
  // kh=1 waves dump O^T partial to LDS (reuse Ks pool: [hd128][q64] fp32 = 32KB)
  float* Oc = (float*)&Ks[0][0];
  if (kh == 1) {
#pragma unroll
    for (int ht = 0; ht < 4; ht++)
#pragma unroll
      for (int r = 0; r < 16; r++) {
        const int hdp = (r & 3) + 8 * (r >> 2) + 4 * hb;
        Oc[(ht * 32 + hdp) * 64 + rh * 32 + l31] = accT[ht][r];
      }
  }
  __syncthreads();
  if (kh == 0) {
    const float rinv = 1.f / (RsD[wave][l31] + RsD[wave + 2][l31]);
    const long orow = (long)(b * Sc + q0 + rh * 32 + l31);
#pragma unroll
    for (int ht = 0; ht < 4; ht++)
#pragma unroll
      for (int g2 = 0; g2 < 4; g2++) {
        bf16x4 ov;
#pragma unroll
        for (int r0 = 0; r0 < 4; r0++) {
          const int hdp = r0 + 8 * g2 + 4 * hb;
          ov[r0] = (bf16_t)((accT[ht][g2 * 4 + r0] +
                             Oc[(ht * 32 + hdp) * 64 + rh * 32 + l31]) * rinv);
        }
        *(bf16x4*)(ctx + orow * Dc + h * HDc + ht * 32 + 8 * g2 + 4 * hb) = ov;
      }
  }
}

// ---------------- workspace layout (bytes) ----------------
constexpr size_t SE_OFF = 0;                       // fp32 8192x512   (16 MB)
constexpr size_t SQB_OFF = 16777216;               // bf16 8192x512: squeeze out, later ctx
constexpr size_t SEB_OFF = 25165824;               // bf16 8192x512: se bf16; later pos2
constexpr size_t Q_OFF = 33554432;                 // bf16 8192x512 (aliases Xb)
constexpr size_t K_OFF = 41943040;                 // bf16 tiled 8 MB (h first half)
constexpr size_t V_OFF = 50331648;                 // bf16 tiled 8 MB (h second half)
constexpr size_t XB_OFF = Q_OFF;                   // bf16 X copy, dead before q written
constexpr size_t H_OFF = K_OFF;                    // bf16 8192x1024, dead before k/v written
constexpr size_t POS2_OFF = SEB_OFF;               // float4 x 8192 = 128 KB, after seb dead
constexpr size_t WTE_OFF = 58720256;               // bf16 1024x512
constexpr size_t WTS_OFF = WTE_OFF + 1048576;      // bf16 512x1024
constexpr size_t WTQKV_OFF = WTS_OFF + 1048576;    // bf16 1536x512
// end = 62,390,272 bytes

extern "C" void kernel_launch(void* const* d_in, const int* in_sizes, int n_in,
                              void* d_out, int out_size, void* d_ws, size_t ws_size,
                              hipStream_t stream) {
  const float* X = (const float*)d_in[0];
  const float* pos = (const float*)d_in[1];
  const float* W_expand = (const float*)d_in[2];
  const float* b_expand = (const float*)d_in[3];
  const float* W_squeeze = (const float*)d_in[4];
  const float* b_squeeze = (const float*)d_in[5];
  const float* gamma = (const float*)d_in[6];
  const float* beta = (const float*)d_in[7];
  const float* Wq = (const float*)d_in[8];
  const float* bq = (const float*)d_in[9];
  const float* Wk = (const float*)d_in[10];
  const float* bk = (const float*)d_in[11];
  const float* Wv = (const float*)d_in[12];
  const float* bv = (const float*)d_in[13];
  const float* alphap = (const float*)d_in[14];

  char* ws = (char*)d_ws;
  float* se = (float*)(ws + SE_OFF);
  bf16_t* sqb = (bf16_t*)(ws + SQB_OFF);
  bf16_t* ctxb = (bf16_t*)(ws + SQB_OFF);  // reuses sqb slot (sq dead after LN)
  bf16_t* seb = (bf16_t*)(ws + SEB_OFF);
  float* pos2 = (float*)(ws + POS2_OFF);   // written after seb is dead
  bf16_t* qb = (bf16_t*)(ws + Q_OFF);
  bf16_t* kb = (bf16_t*)(ws + K_OFF);
  bf16_t* vb = (bf16_t*)(ws + V_OFF);
  bf16_t* xbb = (bf16_t*)(ws + XB_OFF);
  bf16_t* hb = (bf16_t*)(ws + H_OFF);
  bf16_t* wtE = (bf16_t*)(ws + WTE_OFF);
  bf16_t* wtS = (bf16_t*)(ws + WTS_OFF);
  bf16_t* wtQKV = (bf16_t*)(ws + WTQKV_OFF);

  // fused prep: X->bf16 + all weight transposes
  prep_k<<<3840, 256, 0, stream>>>(X, xbb, W_expand, wtE, W_squeeze, wtS,
                                   Wq, Wk, Wv, wtQKV);
  // h = relu(X @ We + be)            [8192,1024] bf16
  gemm128_k<0, 128><<<dim3(1024 / 128, Mrows / 128), 256, 0, stream>>>(
      xbb, wtE, b_expand, nullptr, nullptr, hb, nullptr, nullptr, 1024, 512);
  // sq = h @ Ws + bs                 [8192,512] bf16 (TN=64: 512 blocks)
  gemm128_k<1, 64><<<dim3(512 / 64, Mrows / 128), 256, 0, stream>>>(
      hb, wtS, b_squeeze, nullptr, nullptr, sqb, nullptr, nullptr, 512, 1024);
  // se = LN(X + sq)  (fp32 + bf16 copy)
  ln_k<1><<<Mrows / 4, 256, 0, stream>>>(X, sqb, gamma, beta, se, seb);
  // q,k,v = se @ [Wq|Wk|Wv] + b      q row-major; k,v frag-native tiled
  gemm128_k<2, 128><<<dim3(1536 / 128, Mrows / 128), 256, 0, stream>>>(
      seb, wtQKV, bq, bk, bv, qb, kb, vb, 1536, 512);
  // pack positions (seb dead -> pos2 aliases it)
  pospack_k<<<Mrows / 256, 256, 0, stream>>>(pos, alphap, pos2);
  // ctx = attention                  [8192,512] bf16
  attn_k<<<dim3(Sc / 64, Hc, Bc), 256, 0, stream>>>(qb, kb, vb, pos2, alphap, ctxb);
  // out = LN(se + ctx)
  ln_k<0><<<Mrows / 4, 256, 0, stream>>>(se, ctxb, gamma, beta, (float*)d_out, nullptr);

  (void)in_sizes; (void)n_in; (void)out_size; (void)ws_size;
}

// Round 8
// 222.213 us; speedup vs baseline: 1.6009x; 1.0510x over previous
//
#include <hip/hip_runtime.h>

typedef __bf16 bf16_t;
typedef __attribute__((ext_vector_type(8))) __bf16 bf16x8;
typedef __attribute__((ext_vector_type(4))) __bf16 bf16x4;
typedef __attribute__((ext_vector_type(4))) float f32x4;
typedef __attribute__((ext_vector_type(16))) float f32x16;

constexpr int Bc = 4, Sc = 2048, Dc = 512, Hc = 4, HDc = 128;
constexpr int Mrows = Bc * Sc;  // 8192

// gl2lds contract (r5/r6 lesson): source address MUST be per-lane (any per-lane
// permutation ok — it's a gather); LDS dest is wave-uniform base + lane*16.
__device__ inline void gl2lds(const void* g, void* l) {
  __builtin_amdgcn_global_load_lds(
      (__attribute__((address_space(1))) void*)g,
      (__attribute__((address_space(3))) void*)l, 16, 0, 0);
}

// ---------- fused prep: X->bf16 cast + pos pack + 5 weight transposes ----------
__global__ __launch_bounds__(256) void prep_k(
    const float* __restrict__ X, bf16_t* __restrict__ xb,
    const float* __restrict__ pos, const float* __restrict__ alphap,
    float* __restrict__ pos2,
    const float* __restrict__ We, bf16_t* __restrict__ wtE,
    const float* __restrict__ Ws, bf16_t* __restrict__ wtS,
    const float* __restrict__ Wq, const float* __restrict__ Wk,
    const float* __restrict__ Wv, bf16_t* __restrict__ wtQKV) {
  const int bid = blockIdx.x;
  if (bid < 2048) {  // X -> bf16
    const long i = ((long)bid * 256 + threadIdx.x) * 8;
    const float4 a = *(const float4*)(X + i);
    const float4 c = *(const float4*)(X + i + 4);
    bf16x8 o;
    o[0] = (bf16_t)a.x; o[1] = (bf16_t)a.y; o[2] = (bf16_t)a.z; o[3] = (bf16_t)a.w;
    o[4] = (bf16_t)c.x; o[5] = (bf16_t)c.y; o[6] = (bf16_t)c.z; o[7] = (bf16_t)c.w;
    *(bf16x8*)(xb + i) = o;
    return;
  }
  if (bid < 2080) {  // pos2[s] = (x, y, z, -alpha*log2e*|p|^2)
    const float aL = alphap[0] * 1.4426950408889634f;
    const int i = (bid - 2048) * 256 + threadIdx.x;
    const float x = pos[(long)i * 3], y = pos[(long)i * 3 + 1], z = pos[(long)i * 3 + 2];
    float4 o; o.x = x; o.y = y; o.z = z; o.w = -aL * (x * x + y * y + z * z);
    *(float4*)(pos2 + (long)i * 4) = o;
    return;
  }
  __shared__ float tile[32][33];
  const float* src; bf16_t* dst; int K, N, local;
  if (bid < 2592)      { src = We; dst = wtE; K = 512;  N = 1024; local = bid - 2080; }
  else if (bid < 3104) { src = Ws; dst = wtS; K = 1024; N = 512;  local = bid - 2592; }
  else if (bid < 3360) { src = Wq; dst = wtQKV;          K = 512; N = 512; local = bid - 3104; }
  else if (bid < 3616) { src = Wk; dst = wtQKV + 262144; K = 512; N = 512; local = bid - 3360; }
  else                 { src = Wv; dst = wtQKV + 524288; K = 512; N = 512; local = bid - 3616; }
  const int nb = N / 32;
  const int n0 = (local % nb) * 32, k0 = (local / nb) * 32;
  const int tx = threadIdx.x & 31, ty = threadIdx.x >> 5;
#pragma unroll
  for (int i = 0; i < 4; i++)
    tile[ty + i * 8][tx] = src[(long)(k0 + ty + i * 8) * N + n0 + tx];
  __syncthreads();
#pragma unroll
  for (int i = 0; i < 4; i++)
    dst[(long)(n0 + ty + i * 8) * K + k0 + tx] = (bf16_t)tile[tx][ty + i * 8];
}

// ---------- 128xTN MFMA GEMM, BK=64, dbuf + XOR-swizzled LDS + XCD row-swizzle ----
// grid = 1-D (NB*64); same-row blocks co-located per XCD (B L2-resident, A exclusive)
// OMODE: 0 = relu+bias -> bf16 ; 1 = bias -> bf16 ; 2 = qkv scatter bf16
template <int OMODE, int TN, int NB>
__global__ __launch_bounds__(256, (TN == 128) ? 2 : 3) void gemm128_k(
    const bf16_t* __restrict__ A, const bf16_t* __restrict__ Bt,
    const float* __restrict__ bias0, const float* __restrict__ bias1,
    const float* __restrict__ bias2, void* __restrict__ out0,
    void* __restrict__ out1, void* __restrict__ out2, int N, int K) {
  __shared__ bf16_t As[2][128 * 64];
  __shared__ bf16_t Bs[2][TN * 64];
  constexpr int MT = (TN == 128) ? 4 : 2;
  constexpr int BI = (TN == 128) ? 4 : 2;
  constexpr int MW = (TN == 128) ? 64 : 32;
  const int t = threadIdx.x;
  // XCD swizzle: xcd = p&7 = row%8; all NB col-blocks of a row on one XCD
  const int p = blockIdx.x;
  const int slot = p >> 3;
  const int by = (p & 7) + 8 * (slot / NB);
  const int bx = slot % NB;
  const int n0 = bx * TN, m0 = by * 128;
  const int lane = t & 63, wave = t >> 6;
  const int quad = lane >> 4, ln = lane & 15;
  const int wm = (TN == 128) ? (wave >> 1) : wave;
  const int wn = (TN == 128) ? (wave & 1) : 0;
  const int l8 = lane >> 3, g = lane & 7;
  const bf16_t* aseg = A + (long)(m0 + wave * 32 + l8) * K + (g ^ l8) * 8;
  const bf16_t* bseg = Bt + (long)(n0 + wave * (BI * 8) + l8) * K + (g ^ l8) * 8;
  auto stage = [&](int buf, int k0) {
#pragma unroll
    for (int i = 0; i < 4; i++)
      gl2lds(aseg + (long)i * 8 * K + k0, &As[buf][(wave * 32 + i * 8) * 64]);
#pragma unroll
    for (int i = 0; i < BI; i++)
      gl2lds(bseg + (long)i * 8 * K + k0, &Bs[buf][(wave * BI * 8 + i * 8) * 64]);
  };
  f32x4 acc[MT][4] = {};
  stage(0, 0);
  const int niter = K / 64;
  for (int it = 0; it < niter; it++) {
    const int cur = it & 1;
    __syncthreads();
    if (it + 1 < niter) stage(1 - cur, (it + 1) * 64);
#pragma unroll
    for (int kc = 0; kc < 2; kc++) {
      bf16x8 af[MT], bfr[4];
#pragma unroll
      for (int mt = 0; mt < MT; mt++)
        af[mt] = *(const bf16x8*)&As[cur][(wm * MW + mt * 16 + ln) * 64 +
                                          (((kc * 4 + quad) ^ (ln & 7)) * 8)];
#pragma unroll
      for (int nt = 0; nt < 4; nt++)
        bfr[nt] = *(const bf16x8*)&Bs[cur][(wn * 64 + nt * 16 + ln) * 64 +
                                           (((kc * 4 + quad) ^ (ln & 7)) * 8)];
#pragma unroll
      for (int mt = 0; mt < MT; mt++)
#pragma unroll
        for (int nt = 0; nt < 4; nt++)
          acc[mt][nt] = __builtin_amdgcn_mfma_f32_16x16x32_bf16(af[mt], bfr[nt],
                                                                acc[mt][nt], 0, 0, 0);
    }
  }
#pragma unroll
  for (int nt = 0; nt < 4; nt++) {
    const int gcol = n0 + wn * 64 + nt * 16 + ln;
    if constexpr (OMODE == 0 || OMODE == 1) {
      const float bv = bias0[gcol];
      bf16_t* o = (bf16_t*)out0;
#pragma unroll
      for (int mt = 0; mt < MT; mt++)
#pragma unroll
        for (int r = 0; r < 4; r++) {
          const int grow = m0 + wm * MW + mt * 16 + quad * 4 + r;
          float vv = acc[mt][nt][r] + bv;
          if constexpr (OMODE == 0) vv = vv > 0.f ? vv : 0.f;
          o[(long)grow * N + gcol] = (bf16_t)vv;
        }
    } else {
      const int which = gcol >> 9, n = gcol & 511;
      const int hh = n >> 7, hd = n & 127;
      const float bv = (which == 0 ? bias0 : which == 1 ? bias1 : bias2)[n];
      bf16_t* o = (bf16_t*)(which == 0 ? out0 : which == 1 ? out1 : out2);
#pragma unroll
      for (int mt = 0; mt < MT; mt++)
#pragma unroll
        for (int r = 0; r < 4; r++) {
          const int grow = m0 + wm * MW + mt * 16 + quad * 4 + r;
          const int b = grow >> 11, s = grow & 2047;
          const float vv = acc[mt][nt][r] + bv;
          long idx;
          if (which == 0) {  // q: [b,h,s,128] row-major
            idx = ((long)((b * Hc + hh) * Sc + s)) * HDc + hd;
          } else if (which == 1) {  // k frag-native: [b,h,t][kh][c][lane][8]
            const int tt = s >> 6, kh = (s >> 5) & 1, key = s & 31;
            const int c = hd >> 4, lk = key + 32 * ((hd >> 3) & 1), j = hd & 7;
            idx = ((((long)((b * Hc + hh) * 32 + tt) * 2 + kh) * 8 + c) * 64 + lk) * 8 + j;
          } else {  // v frag-native: [b,h,t][ht][kc][lane][8]
            const int tt = s >> 6, ht2 = hd >> 5, kc = (s & 63) >> 4;
            const int lk = (hd & 31) + 32 * ((s >> 3) & 1), j = s & 7;
            idx = ((((long)((b * Hc + hh) * 32 + tt) * 4 + ht2) * 4 + kc) * 64 + lk) * 8 + j;
          }
          o[idx] = (bf16_t)vv;
        }
    }
  }
}

// ---------- LayerNorm(xa + xb): one wave per row of 512, lane = 8 cols ----------
// AF32: xa is fp32 (else bf16). OF32: write fp32 out (else bf16).
template <int AF32, int OF32>
__global__ __launch_bounds__(256) void ln_k(const void* __restrict__ xa,
                                            const bf16_t* __restrict__ xb,
                                            const float* __restrict__ gamma,
                                            const float* __restrict__ beta,
                                            void* __restrict__ out) {
  const int wave = threadIdx.x >> 6, lane = threadIdx.x & 63;
  const long row = (long)blockIdx.x * 4 + wave;
  const int col0 = lane * 8;
  float vv[8];
  float s = 0.f, s2 = 0.f;
  const bf16x8 vb = *(const bf16x8*)(xb + row * Dc + col0);
  if constexpr (AF32) {
    const float* a = (const float*)xa + row * Dc + col0;
    const float4 a0 = *(const float4*)a;
    const float4 a1 = *(const float4*)(a + 4);
    const float xs[8] = {a0.x, a0.y, a0.z, a0.w, a1.x, a1.y, a1.z, a1.w};
#pragma unroll
    for (int j = 0; j < 8; j++) vv[j] = xs[j] + (float)vb[j];
  } else {
    const bf16x8 va = *(const bf16x8*)((const bf16_t*)xa + row * Dc + col0);
#pragma unroll
    for (int j = 0; j < 8; j++) vv[j] = (float)va[j] + (float)vb[j];
  }
#pragma unroll
  for (int j = 0; j < 8; j++) { s += vv[j]; s2 += vv[j] * vv[j]; }
#pragma unroll
  for (int off = 1; off < 64; off <<= 1) {
    s += __shfl_xor(s, off, 64);
    s2 += __shfl_xor(s2, off, 64);
  }
  const float mu = s * (1.f / Dc);
  const float var = s2 * (1.f / Dc) - mu * mu;
  const float rstd = rsqrtf(var + 1e-5f);
  const float4 g0 = *(const float4*)(gamma + col0);
  const float4 g1 = *(const float4*)(gamma + col0 + 4);
  const float4 b0 = *(const float4*)(beta + col0);
  const float4 b1 = *(const float4*)(beta + col0 + 4);
  const float gs[8] = {g0.x, g0.y, g0.z, g0.w, g1.x, g1.y, g1.z, g1.w};
  const float bs[8] = {b0.x, b0.y, b0.z, b0.w, b1.x, b1.y, b1.z, b1.w};
  if constexpr (OF32) {
    float* o = (float*)out + row * Dc + col0;
    float4 o0, o1;
    o0.x = (vv[0] - mu) * rstd * gs[0] + bs[0];
    o0.y = (vv[1] - mu) * rstd * gs[1] + bs[1];
    o0.z = (vv[2] - mu) * rstd * gs[2] + bs[2];
    o0.w = (vv[3] - mu) * rstd * gs[3] + bs[3];
    o1.x = (vv[4] - mu) * rstd * gs[4] + bs[4];
    o1.y = (vv[5] - mu) * rstd * gs[5] + bs[5];
    o1.z = (vv[6] - mu) * rstd * gs[6] + bs[6];
    o1.w = (vv[7] - mu) * rstd * gs[7] + bs[7];
    *(float4*)o = o0; *(float4*)(o + 4) = o1;
  } else {
    bf16x8 ob;
#pragma unroll
    for (int j = 0; j < 8; j++) ob[j] = (bf16_t)((vv[j] - mu) * rstd * gs[j] + bs[j]);
    *(bf16x8*)((bf16_t*)out + row * Dc + col0) = ob;
  }
}

// ---------- flash attention: S^T = K Q^T, 32x32 MFMA, XCD-swizzled grid ----------
// grid 1-D 512: all 32 q-tiles of one (b,h) on one XCD (K/V stream L2-resident)
__global__ __launch_bounds__(256, 2) void attn_k(const bf16_t* __restrict__ q,
                                                 const bf16_t* __restrict__ Kg,
                                                 const bf16_t* __restrict__ Vg,
                                                 const float* __restrict__ pos2,
                                                 const float* __restrict__ alphap,
                                                 bf16_t* __restrict__ ctx) {
  __shared__ bf16_t Ks[2][8192];   // [kh][c][lane][8] frag-native
  __shared__ bf16_t Vts[2][8192];  // [ht][kc][lane][8]
  __shared__ float pk4[2][64][4];  // key positions (x,y,z,-aL|p|^2)
  __shared__ bf16_t Ps[4][1024];   // per-wave P^T B-frags [c2][lane][8]
  __shared__ float RsD[4][32];
  const int t = threadIdx.x;
  // XCD swizzle: g = (b,h) group = (p&7) + 8*(p>>8); qt = (p>>3)&31
  const int p = blockIdx.x;
  const int qt = (p >> 3) & 31;
  const int gg = (p & 7) + 8 * (p >> 8);
  const int h = gg & 3, b = gg >> 2;
  const int q0 = qt * 64;
  const int wave = t >> 6, lane = t & 63;
  const int l31 = lane & 31, hb = lane >> 5;
  const int rh = wave & 1, kh = wave >> 1;
  const float l2e = 1.4426950408889634f;
  const float scale_l2 = l2e * 0.08838834764831845f;  // log2e/sqrt(128)
  const float aL = alphap[0] * l2e;

  // Q fragments (B-operand): q-row = q0+rh*32+l31 (lane-fixed)
  bf16x8 qf[8];
  const long qrow = (long)((b * Hc + h) * Sc + q0 + rh * 32 + l31);
#pragma unroll
  for (int c = 0; c < 8; c++)
    qf[c] = *(const bf16x8*)(q + qrow * HDc + c * 16 + hb * 8);
  float pqx, pqy, pqz;
  {
    const float4 pv = *(const float4*)(pos2 + (long)(b * Sc + q0 + rh * 32 + l31) * 4);
    pqx = 2.f * aL * pv.x; pqy = 2.f * aL * pv.y; pqz = 2.f * aL * pv.z;
  }

  const bf16_t* ktile = Kg + (long)((b * Hc + h) * 32) * 8192 + lane * 8;
  const bf16_t* vtile = Vg + (long)((b * Hc + h) * 32) * 8192 + lane * 8;
  const float* pcur = pos2 + (long)b * Sc * 4 + lane * 4;
  auto stage = [&](int buf) {
#pragma unroll
    for (int i = 0; i < 4; i++)
      gl2lds(ktile + (wave * 4 + i) * 512, &Ks[buf][(wave * 4 + i) * 512]);
#pragma unroll
    for (int i = 0; i < 4; i++)
      gl2lds(vtile + (wave * 4 + i) * 512, &Vts[buf][(wave * 4 + i) * 512]);
    if (wave == 0) gl2lds(pcur, &pk4[buf][0][0]);
  };
  stage(0);
  ktile += 8192; vtile += 8192; pcur += 256;

  float rsl = 0.f;
  f32x16 accT[4] = {};
  // P^T B-frag write base (8B-aligned): (key kp, q l31) -> c2*512+(l31+32*((kp>>3)&1))*8+(kp&7)
  bf16_t* pwbase = &Ps[wave][l31 * 8 + 4 * hb];

  for (int kt = 0; kt < Sc / 64; kt++) {
    const int cur = kt & 1;
    __syncthreads();
    if (kt < Sc / 64 - 1) {
      stage(1 - cur);
      ktile += 8192; vtile += 8192; pcur += 256;
    }
    // S^T = K Q^T
    f32x16 sacc = {};
#pragma unroll
    for (int c = 0; c < 8; c++) {
      const bf16x8 kf = *(const bf16x8*)&Ks[cur][(kh * 8 + c) * 512 + lane * 8];
      sacc = __builtin_amdgcn_mfma_f32_32x32x16_bf16(kf, qf[c], sacc, 0, 0, 0);
    }
    // p = 2^(s*scale + pk.w + pq2aL.pk); pack 4 per b64 LDS store
#pragma unroll
    for (int g2 = 0; g2 < 4; g2++) {
      bf16x4 pq4;
#pragma unroll
      for (int r0 = 0; r0 < 4; r0++) {
        const int kp = r0 + 4 * hb + 8 * g2;
        const float4 pv = *(const float4*)&pk4[cur][kh * 32 + kp][0];
        const float bias = __builtin_fmaf(pqx, pv.x,
                           __builtin_fmaf(pqy, pv.y,
                           __builtin_fmaf(pqz, pv.z, pv.w)));
        const float pe = __builtin_amdgcn_exp2f(
            __builtin_fmaf(sacc[g2 * 4 + r0], scale_l2, bias));
        rsl += pe;
        pq4[r0] = (bf16_t)pe;
      }
      *(bf16x4*)(pwbase + (g2 >> 1) * 512 + (g2 & 1) * 256) = pq4;
    }
    // O^T += V^T P^T
    const bf16x8 pf0 = *(const bf16x8*)&Ps[wave][lane * 8];
    const bf16x8 pf1 = *(const bf16x8*)&Ps[wave][512 + lane * 8];
#pragma unroll
    for (int ht = 0; ht < 4; ht++) {
      const bf16x8 v0 = *(const bf16x8*)&Vts[cur][(ht * 4 + kh * 2 + 0) * 512 + lane * 8];
      accT[ht] = __builtin_amdgcn_mfma_f32_32x32x16_bf16(v0, pf0, accT[ht], 0, 0, 0);
      const bf16x8 v1 = *(const bf16x8*)&Vts[cur][(ht * 4 + kh * 2 + 1) * 512 + lane * 8];
      accT[ht] = __builtin_amdgcn_mfma_f32_32x32x16_bf16(v1, pf1, accT[ht], 0, 0, 0);
    }
  }
  __syncthreads();

  rsl += __shfl_xor(rsl, 32, 64);
  if (hb == 0) RsD[wave][l31] = rsl;
  float* Oc = (float*)&Ks[0][0];
  if (kh == 1) {
#pragma unroll
    for (int ht = 0; ht < 4; ht++)
#pragma unroll
      for (int r = 0; r < 16; r++) {
        const int hdp = (r & 3) + 8 * (r >> 2) + 4 * hb;
        Oc[(ht * 32 + hdp) * 64 + rh * 32 + l31] = accT[ht][r];
      }
  }
  __syncthreads();
  if (kh == 0) {
    const float rinv = 1.f / (RsD[wave][l31] + RsD[wave + 2][l31]);
    const long orow = (long)(b * Sc + q0 + rh * 32 + l31);
#pragma unroll
    for (int ht = 0; ht < 4; ht++)
#pragma unroll
      for (int g2 = 0; g2 < 4; g2++) {
        bf16x4 ov;
#pragma unroll
        for (int r0 = 0; r0 < 4; r0++) {
          const int hdp = r0 + 8 * g2 + 4 * hb;
          ov[r0] = (bf16_t)((accT[ht][g2 * 4 + r0] +
                             Oc[(ht * 32 + hdp) * 64 + rh * 32 + l31]) * rinv);
        }
        *(bf16x4*)(ctx + orow * Dc + h * HDc + ht * 32 + 8 * g2 + 4 * hb) = ov;
      }
  }
}

// ---------------- workspace layout (bytes) ----------------
constexpr size_t SQB_OFF = 0;                      // bf16 8192x512: squeeze out, later ctx
constexpr size_t SEB_OFF = 8388608;                // bf16 8192x512: se
constexpr size_t Q_OFF = 16777216;                 // bf16 8192x512 (Xb aliases)
constexpr size_t K_OFF = 25165824;                 // bf16 tiled 8 MB (h first half)
constexpr size_t V_OFF = 33554432;                 // bf16 tiled 8 MB (h second half)
constexpr size_t XB_OFF = Q_OFF;                   // bf16 X copy, dead before q written
constexpr size_t H_OFF = K_OFF;                    // bf16 8192x1024, dead before k/v written
constexpr size_t POS2_OFF = 41943040;              // float4 x 8192 = 128 KB (own slot)
constexpr size_t WTE_OFF = POS2_OFF + 131072;      // bf16 1024x512 (1 MB)
constexpr size_t WTS_OFF = WTE_OFF + 1048576;      // bf16 512x1024 (1 MB)
constexpr size_t WTQKV_OFF = WTS_OFF + 1048576;    // bf16 1536x512 (1.5 MB)
// end = 45,647,872 bytes

extern "C" void kernel_launch(void* const* d_in, const int* in_sizes, int n_in,
                              void* d_out, int out_size, void* d_ws, size_t ws_size,
                              hipStream_t stream) {
  const float* X = (const float*)d_in[0];
  const float* pos = (const float*)d_in[1];
  const float* W_expand = (const float*)d_in[2];
  const float* b_expand = (const float*)d_in[3];
  const float* W_squeeze = (const float*)d_in[4];
  const float* b_squeeze = (const float*)d_in[5];
  const float* gamma = (const float*)d_in[6];
  const float* beta = (const float*)d_in[7];
  const float* Wq = (const float*)d_in[8];
  const float* bq = (const float*)d_in[9];
  const float* Wk = (const float*)d_in[10];
  const float* bk = (const float*)d_in[11];
  const float* Wv = (const float*)d_in[12];
  const float* bv = (const float*)d_in[13];
  const float* alphap = (const float*)d_in[14];

  char* ws = (char*)d_ws;
  bf16_t* sqb = (bf16_t*)(ws + SQB_OFF);
  bf16_t* ctxb = (bf16_t*)(ws + SQB_OFF);  // reuses sqb (sq dead after LN1)
  bf16_t* seb = (bf16_t*)(ws + SEB_OFF);
  float* pos2 = (float*)(ws + POS2_OFF);
  bf16_t* qb = (bf16_t*)(ws + Q_OFF);
  bf16_t* kb = (bf16_t*)(ws + K_OFF);
  bf16_t* vb = (bf16_t*)(ws + V_OFF);
  bf16_t* xbb = (bf16_t*)(ws + XB_OFF);
  bf16_t* hb = (bf16_t*)(ws + H_OFF);
  bf16_t* wtE = (bf16_t*)(ws + WTE_OFF);
  bf16_t* wtS = (bf16_t*)(ws + WTS_OFF);
  bf16_t* wtQKV = (bf16_t*)(ws + WTQKV_OFF);

  // prep: X cast + pos pack + weight transposes (one launch)
  prep_k<<<3872, 256, 0, stream>>>(X, xbb, pos, alphap, pos2,
                                   W_expand, wtE, W_squeeze, wtS, Wq, Wk, Wv, wtQKV);
  // h = relu(X @ We + be)            [8192,1024] bf16
  gemm128_k<0, 128, 8><<<512, 256, 0, stream>>>(
      xbb, wtE, b_expand, nullptr, nullptr, hb, nullptr, nullptr, 1024, 512);
  // sq = h @ Ws + bs                 [8192,512] bf16
  gemm128_k<1, 64, 8><<<512, 256, 0, stream>>>(
      hb, wtS, b_squeeze, nullptr, nullptr, sqb, nullptr, nullptr, 512, 1024);
  // se = LN(X + sq)  -> bf16
  ln_k<1, 0><<<Mrows / 4, 256, 0, stream>>>(X, sqb, gamma, beta, seb);
  // q,k,v = se @ [Wq|Wk|Wv] + b
  gemm128_k<2, 128, 12><<<768, 256, 0, stream>>>(
      seb, wtQKV, bq, bk, bv, qb, kb, vb, 1536, 512);
  // ctx = attention
  attn_k<<<512, 256, 0, stream>>>(qb, kb, vb, pos2, alphap, ctxb);
  // out = LN(se + ctx) -> fp32
  ln_k<0, 1><<<Mrows / 4, 256, 0, stream>>>(seb, ctxb, gamma, beta, (float*)d_out);

  (void)in_sizes; (void)n_in; (void)out_size; (void)ws_size;
}

// Round 9
// 214.724 us; speedup vs baseline: 1.6567x; 1.0349x over previous
//
#include <hip/hip_runtime.h>

typedef __bf16 bf16_t;
typedef __attribute__((ext_vector_type(8))) __bf16 bf16x8;
typedef __attribute__((ext_vector_type(4))) __bf16 bf16x4;
typedef __attribute__((ext_vector_type(4))) float f32x4;
typedef __attribute__((ext_vector_type(16))) float f32x16;

constexpr int Bc = 4, Sc = 2048, Dc = 512, Hc = 4, HDc = 128;
constexpr int Mrows = Bc * Sc;  // 8192

// gl2lds contract (r5/r6 lesson): source address MUST be per-lane (any per-lane
// permutation ok — it's a gather); LDS dest is wave-uniform base + lane*16.
__device__ inline void gl2lds(const void* g, void* l) {
  __builtin_amdgcn_global_load_lds(
      (__attribute__((address_space(1))) void*)g,
      (__attribute__((address_space(3))) void*)l, 16, 0, 0);
}

// ---------- fused prep: X->bf16 + bias-frag pack + 5 weight transposes ----------
// Qbg[b,s,16] = [2a'x, 2a'y, 2a'z, 1, 0...]          (B-operand bias chunk)
// Kbg tile[b][t][kh][lane][8]: lane<32: key=lane, dims0-7 = [x,y,z,-a'|p|^2,0..];
//   lanes 32-63 (dims 8-15) = 0.  a' = alpha*sqrt(128).
__global__ __launch_bounds__(256) void prep_k(
    const float* __restrict__ X, bf16_t* __restrict__ xb,
    const float* __restrict__ pos, const float* __restrict__ alphap,
    bf16_t* __restrict__ Qbg, bf16_t* __restrict__ Kbg,
    const float* __restrict__ We, bf16_t* __restrict__ wtE,
    const float* __restrict__ Ws, bf16_t* __restrict__ wtS,
    const float* __restrict__ Wq, const float* __restrict__ Wk,
    const float* __restrict__ Wv, bf16_t* __restrict__ wtQKV) {
  const int bid = blockIdx.x;
  if (bid < 2048) {  // X -> bf16
    const long i = ((long)bid * 256 + threadIdx.x) * 8;
    const float4 a = *(const float4*)(X + i);
    const float4 c = *(const float4*)(X + i + 4);
    bf16x8 o;
    o[0] = (bf16_t)a.x; o[1] = (bf16_t)a.y; o[2] = (bf16_t)a.z; o[3] = (bf16_t)a.w;
    o[4] = (bf16_t)c.x; o[5] = (bf16_t)c.y; o[6] = (bf16_t)c.z; o[7] = (bf16_t)c.w;
    *(bf16x8*)(xb + i) = o;
    return;
  }
  if (bid < 2080) {  // position bias fragments
    const float ap = alphap[0] * 11.313708498984761f;  // alpha*sqrt(128)
    const int i = (bid - 2048) * 256 + threadIdx.x;    // b*2048+s
    const int b = i >> 11, s = i & 2047;
    const float x = pos[(long)i * 3], y = pos[(long)i * 3 + 1], z = pos[(long)i * 3 + 2];
    const float m2 = -ap * (x * x + y * y + z * z);
    bf16x8 qlo = {}, klo = {}, zer = {};
    qlo[0] = (bf16_t)(2.f * ap * x); qlo[1] = (bf16_t)(2.f * ap * y);
    qlo[2] = (bf16_t)(2.f * ap * z); qlo[3] = (bf16_t)1.0f;
    klo[0] = (bf16_t)x; klo[1] = (bf16_t)y; klo[2] = (bf16_t)z; klo[3] = (bf16_t)m2;
    *(bf16x8*)(Qbg + (long)i * 16) = qlo;
    *(bf16x8*)(Qbg + (long)i * 16 + 8) = zer;
    const int t = s >> 6, kh = (s >> 5) & 1, key = s & 31;
    const long kb = ((long)(b * 32 + t) * 2 + kh) * 512 + key * 8;
    *(bf16x8*)(Kbg + kb) = klo;
    *(bf16x8*)(Kbg + kb + 256) = zer;
    return;
  }
  __shared__ float tile[32][33];
  const float* src; bf16_t* dst; int K, N, local;
  if (bid < 2592)      { src = We; dst = wtE; K = 512;  N = 1024; local = bid - 2080; }
  else if (bid < 3104) { src = Ws; dst = wtS; K = 1024; N = 512;  local = bid - 2592; }
  else if (bid < 3360) { src = Wq; dst = wtQKV;          K = 512; N = 512; local = bid - 3104; }
  else if (bid < 3616) { src = Wk; dst = wtQKV + 262144; K = 512; N = 512; local = bid - 3360; }
  else                 { src = Wv; dst = wtQKV + 524288; K = 512; N = 512; local = bid - 3616; }
  const int nb = N / 32;
  const int n0 = (local % nb) * 32, k0 = (local / nb) * 32;
  const int tx = threadIdx.x & 31, ty = threadIdx.x >> 5;
#pragma unroll
  for (int i = 0; i < 4; i++)
    tile[ty + i * 8][tx] = src[(long)(k0 + ty + i * 8) * N + n0 + tx];
  __syncthreads();
#pragma unroll
  for (int i = 0; i < 4; i++)
    dst[(long)(n0 + ty + i * 8) * K + k0 + tx] = (bf16_t)tile[tx][ty + i * 8];
}

// ---------- 128xTN MFMA GEMM, BK=64, dbuf + XOR-swizzled LDS + XCD row-swizzle ----
// OMODE: 0 = relu+bias -> bf16 ; 1 = bias -> bf16 ; 2 = qkv scatter bf16
template <int OMODE, int TN, int NB>
__global__ __launch_bounds__(256, (TN == 128) ? 2 : 3) void gemm128_k(
    const bf16_t* __restrict__ A, const bf16_t* __restrict__ Bt,
    const float* __restrict__ bias0, const float* __restrict__ bias1,
    const float* __restrict__ bias2, void* __restrict__ out0,
    void* __restrict__ out1, void* __restrict__ out2, int N, int K) {
  __shared__ bf16_t As[2][128 * 64];
  __shared__ bf16_t Bs[2][TN * 64];
  constexpr int MT = (TN == 128) ? 4 : 2;
  constexpr int BI = (TN == 128) ? 4 : 2;
  constexpr int MW = (TN == 128) ? 64 : 32;
  const int t = threadIdx.x;
  const int p = blockIdx.x;
  const int slot = p >> 3;
  const int by = (p & 7) + 8 * (slot / NB);
  const int bx = slot % NB;
  const int n0 = bx * TN, m0 = by * 128;
  const int lane = t & 63, wave = t >> 6;
  const int quad = lane >> 4, ln = lane & 15;
  const int wm = (TN == 128) ? (wave >> 1) : wave;
  const int wn = (TN == 128) ? (wave & 1) : 0;
  const int l8 = lane >> 3, g = lane & 7;
  const bf16_t* aseg = A + (long)(m0 + wave * 32 + l8) * K + (g ^ l8) * 8;
  const bf16_t* bseg = Bt + (long)(n0 + wave * (BI * 8) + l8) * K + (g ^ l8) * 8;
  auto stage = [&](int buf, int k0) {
#pragma unroll
    for (int i = 0; i < 4; i++)
      gl2lds(aseg + (long)i * 8 * K + k0, &As[buf][(wave * 32 + i * 8) * 64]);
#pragma unroll
    for (int i = 0; i < BI; i++)
      gl2lds(bseg + (long)i * 8 * K + k0, &Bs[buf][(wave * BI * 8 + i * 8) * 64]);
  };
  f32x4 acc[MT][4] = {};
  stage(0, 0);
  const int niter = K / 64;
  for (int it = 0; it < niter; it++) {
    const int cur = it & 1;
    __syncthreads();
    if (it + 1 < niter) stage(1 - cur, (it + 1) * 64);
#pragma unroll
    for (int kc = 0; kc < 2; kc++) {
      bf16x8 af[MT], bfr[4];
#pragma unroll
      for (int mt = 0; mt < MT; mt++)
        af[mt] = *(const bf16x8*)&As[cur][(wm * MW + mt * 16 + ln) * 64 +
                                          (((kc * 4 + quad) ^ (ln & 7)) * 8)];
#pragma unroll
      for (int nt = 0; nt < 4; nt++)
        bfr[nt] = *(const bf16x8*)&Bs[cur][(wn * 64 + nt * 16 + ln) * 64 +
                                           (((kc * 4 + quad) ^ (ln & 7)) * 8)];
#pragma unroll
      for (int mt = 0; mt < MT; mt++)
#pragma unroll
        for (int nt = 0; nt < 4; nt++)
          acc[mt][nt] = __builtin_amdgcn_mfma_f32_16x16x32_bf16(af[mt], bfr[nt],
                                                                acc[mt][nt], 0, 0, 0);
    }
  }
#pragma unroll
  for (int nt = 0; nt < 4; nt++) {
    const int gcol = n0 + wn * 64 + nt * 16 + ln;
    if constexpr (OMODE == 0 || OMODE == 1) {
      const float bv = bias0[gcol];
      bf16_t* o = (bf16_t*)out0;
#pragma unroll
      for (int mt = 0; mt < MT; mt++)
#pragma unroll
        for (int r = 0; r < 4; r++) {
          const int grow = m0 + wm * MW + mt * 16 + quad * 4 + r;
          float vv = acc[mt][nt][r] + bv;
          if constexpr (OMODE == 0) vv = vv > 0.f ? vv : 0.f;
          o[(long)grow * N + gcol] = (bf16_t)vv;
        }
    } else {
      const int which = gcol >> 9, n = gcol & 511;
      const int hh = n >> 7, hd = n & 127;
      const float bv = (which == 0 ? bias0 : which == 1 ? bias1 : bias2)[n];
      bf16_t* o = (bf16_t*)(which == 0 ? out0 : which == 1 ? out1 : out2);
#pragma unroll
      for (int mt = 0; mt < MT; mt++)
#pragma unroll
        for (int r = 0; r < 4; r++) {
          const int grow = m0 + wm * MW + mt * 16 + quad * 4 + r;
          const int b = grow >> 11, s = grow & 2047;
          const float vv = acc[mt][nt][r] + bv;
          long idx;
          if (which == 0) {  // q: [b,h,s,128] row-major
            idx = ((long)((b * Hc + hh) * Sc + s)) * HDc + hd;
          } else if (which == 1) {  // k frag-native: [b,h,t][kh][c][lane][8]
            const int tt = s >> 6, kh = (s >> 5) & 1, key = s & 31;
            const int c = hd >> 4, lk = key + 32 * ((hd >> 3) & 1), j = hd & 7;
            idx = ((((long)((b * Hc + hh) * 32 + tt) * 2 + kh) * 8 + c) * 64 + lk) * 8 + j;
          } else {  // v frag-native: [b,h,t][ht][kc][lane][8]
            const int tt = s >> 6, ht2 = hd >> 5, kc = (s & 63) >> 4;
            const int lk = (hd & 31) + 32 * ((s >> 3) & 1), j = s & 7;
            idx = ((((long)((b * Hc + hh) * 32 + tt) * 4 + ht2) * 4 + kc) * 64 + lk) * 8 + j;
          }
          o[idx] = (bf16_t)vv;
        }
    }
  }
}

// ---------- LayerNorm(xa + xb): one wave per row of 512, lane = 8 cols ----------
template <int AF32, int OF32>
__global__ __launch_bounds__(256) void ln_k(const void* __restrict__ xa,
                                            const bf16_t* __restrict__ xb,
                                            const float* __restrict__ gamma,
                                            const float* __restrict__ beta,
                                            void* __restrict__ out) {
  const int wave = threadIdx.x >> 6, lane = threadIdx.x & 63;
  const long row = (long)blockIdx.x * 4 + wave;
  const int col0 = lane * 8;
  float vv[8];
  float s = 0.f, s2 = 0.f;
  const bf16x8 vb = *(const bf16x8*)(xb + row * Dc + col0);
  if constexpr (AF32) {
    const float* a = (const float*)xa + row * Dc + col0;
    const float4 a0 = *(const float4*)a;
    const float4 a1 = *(const float4*)(a + 4);
    const float xs[8] = {a0.x, a0.y, a0.z, a0.w, a1.x, a1.y, a1.z, a1.w};
#pragma unroll
    for (int j = 0; j < 8; j++) vv[j] = xs[j] + (float)vb[j];
  } else {
    const bf16x8 va = *(const bf16x8*)((const bf16_t*)xa + row * Dc + col0);
#pragma unroll
    for (int j = 0; j < 8; j++) vv[j] = (float)va[j] + (float)vb[j];
  }
#pragma unroll
  for (int j = 0; j < 8; j++) { s += vv[j]; s2 += vv[j] * vv[j]; }
#pragma unroll
  for (int off = 1; off < 64; off <<= 1) {
    s += __shfl_xor(s, off, 64);
    s2 += __shfl_xor(s2, off, 64);
  }
  const float mu = s * (1.f / Dc);
  const float var = s2 * (1.f / Dc) - mu * mu;
  const float rstd = rsqrtf(var + 1e-5f);
  const float4 g0 = *(const float4*)(gamma + col0);
  const float4 g1 = *(const float4*)(gamma + col0 + 4);
  const float4 b0 = *(const float4*)(beta + col0);
  const float4 b1 = *(const float4*)(beta + col0 + 4);
  const float gs[8] = {g0.x, g0.y, g0.z, g0.w, g1.x, g1.y, g1.z, g1.w};
  const float bs[8] = {b0.x, b0.y, b0.z, b0.w, b1.x, b1.y, b1.z, b1.w};
  if constexpr (OF32) {
    float* o = (float*)out + row * Dc + col0;
    float4 o0, o1;
    o0.x = (vv[0] - mu) * rstd * gs[0] + bs[0];
    o0.y = (vv[1] - mu) * rstd * gs[1] + bs[1];
    o0.z = (vv[2] - mu) * rstd * gs[2] + bs[2];
    o0.w = (vv[3] - mu) * rstd * gs[3] + bs[3];
    o1.x = (vv[4] - mu) * rstd * gs[4] + bs[4];
    o1.y = (vv[5] - mu) * rstd * gs[5] + bs[5];
    o1.z = (vv[6] - mu) * rstd * gs[6] + bs[6];
    o1.w = (vv[7] - mu) * rstd * gs[7] + bs[7];
    *(float4*)o = o0; *(float4*)(o + 4) = o1;
  } else {
    bf16x8 ob;
#pragma unroll
    for (int j = 0; j < 8; j++) ob[j] = (bf16_t)((vv[j] - mu) * rstd * gs[j] + bs[j]);
    *(bf16x8*)((bf16_t*)out + row * Dc + col0) = ob;
  }
}

// ---------- flash attention: S^T = K Q^T + MFMA-folded bias, XCD-swizzled ----------
__global__ __launch_bounds__(256, 2) void attn_k(const bf16_t* __restrict__ q,
                                                 const bf16_t* __restrict__ Kg,
                                                 const bf16_t* __restrict__ Vg,
                                                 const bf16_t* __restrict__ Qbg,
                                                 const bf16_t* __restrict__ Kbg,
                                                 bf16_t* __restrict__ ctx) {
  __shared__ bf16_t Ks[2][8192];   // [kh][c][lane][8] frag-native
  __shared__ bf16_t Vts[2][8192];  // [ht][kc][lane][8]
  __shared__ bf16_t Kb[2][1024];   // [kh][lane][8] bias A-frags
  __shared__ bf16_t Ps[4][1024];   // per-wave P^T B-frags [c2][lane][8]
  __shared__ float RsD[4][32];
  const int t = threadIdx.x;
  const int p = blockIdx.x;
  const int qt = (p >> 3) & 31;
  const int gg = (p & 7) + 8 * (p >> 8);
  const int h = gg & 3, b = gg >> 2;
  const int q0 = qt * 64;
  const int wave = t >> 6, lane = t & 63;
  const int l31 = lane & 31, hb = lane >> 5;
  const int rh = wave & 1, kh = wave >> 1;
  const float scale_l2 = 1.4426950408889634f * 0.08838834764831845f;  // log2e/sqrt(128)

  // Q fragments (B-operand): q-col = q0+rh*32+l31 (lane-fixed); bias chunk from Qbg
  bf16x8 qf[8], qbf;
  const long qrow = (long)((b * Hc + h) * Sc + q0 + rh * 32 + l31);
#pragma unroll
  for (int c = 0; c < 8; c++)
    qf[c] = *(const bf16x8*)(q + qrow * HDc + c * 16 + hb * 8);
  qbf = *(const bf16x8*)(Qbg + (long)(b * Sc + q0 + rh * 32 + l31) * 16 + hb * 8);

  // staging: all sources base + lane*16B (per-lane!)
  const bf16_t* ktile = Kg + (long)((b * Hc + h) * 32) * 8192 + lane * 8;
  const bf16_t* vtile = Vg + (long)((b * Hc + h) * 32) * 8192 + lane * 8;
  const bf16_t* kbtile = Kbg + (long)(b * 32) * 1024 + lane * 8;
  auto stage = [&](int buf) {
#pragma unroll
    for (int i = 0; i < 4; i++)
      gl2lds(ktile + (wave * 4 + i) * 512, &Ks[buf][(wave * 4 + i) * 512]);
#pragma unroll
    for (int i = 0; i < 4; i++)
      gl2lds(vtile + (wave * 4 + i) * 512, &Vts[buf][(wave * 4 + i) * 512]);
    if (wave < 2) gl2lds(kbtile + wave * 512, &Kb[buf][wave * 512]);
  };
  stage(0);
  ktile += 8192; vtile += 8192; kbtile += 1024;

  float rsl = 0.f;
  f32x16 accT[4] = {};
  bf16_t* pwbase = &Ps[wave][l31 * 8 + 4 * hb];

  for (int kt = 0; kt < Sc / 64; kt++) {
    const int cur = kt & 1;
    __syncthreads();
    if (kt < Sc / 64 - 1) {
      stage(1 - cur);
      ktile += 8192; vtile += 8192; kbtile += 1024;
    }
    // S^T = K Q^T + folded dist bias — two independent accumulator chains
    f32x16 sa = {}, sb = {};
#pragma unroll
    for (int c = 0; c < 4; c++) {
      const bf16x8 kf = *(const bf16x8*)&Ks[cur][(kh * 8 + c) * 512 + lane * 8];
      sa = __builtin_amdgcn_mfma_f32_32x32x16_bf16(kf, qf[c], sa, 0, 0, 0);
    }
#pragma unroll
    for (int c = 4; c < 8; c++) {
      const bf16x8 kf = *(const bf16x8*)&Ks[cur][(kh * 8 + c) * 512 + lane * 8];
      sb = __builtin_amdgcn_mfma_f32_32x32x16_bf16(kf, qf[c], sb, 0, 0, 0);
    }
    {
      const bf16x8 kbf = *(const bf16x8*)&Kb[cur][kh * 512 + lane * 8];
      sb = __builtin_amdgcn_mfma_f32_32x32x16_bf16(kbf, qbf, sb, 0, 0, 0);
    }
    const f32x16 sacc = sa + sb;
    // p = 2^(sacc * scale_l2); pack 4 per b64 LDS store
#pragma unroll
    for (int g2 = 0; g2 < 4; g2++) {
      bf16x4 pq4;
#pragma unroll
      for (int r0 = 0; r0 < 4; r0++) {
        const float pe = __builtin_amdgcn_exp2f(sacc[g2 * 4 + r0] * scale_l2);
        rsl += pe;
        pq4[r0] = (bf16_t)pe;
      }
      *(bf16x4*)(pwbase + (g2 >> 1) * 512 + (g2 & 1) * 256) = pq4;
    }
    // O^T += V^T P^T
    const bf16x8 pf0 = *(const bf16x8*)&Ps[wave][lane * 8];
    const bf16x8 pf1 = *(const bf16x8*)&Ps[wave][512 + lane * 8];
#pragma unroll
    for (int ht = 0; ht < 4; ht++) {
      const bf16x8 v0 = *(const bf16x8*)&Vts[cur][(ht * 4 + kh * 2 + 0) * 512 + lane * 8];
      accT[ht] = __builtin_amdgcn_mfma_f32_32x32x16_bf16(v0, pf0, accT[ht], 0, 0, 0);
      const bf16x8 v1 = *(const bf16x8*)&Vts[cur][(ht * 4 + kh * 2 + 1) * 512 + lane * 8];
      accT[ht] = __builtin_amdgcn_mfma_f32_32x32x16_bf16(v1, pf1, accT[ht], 0, 0, 0);
    }
  }
  __syncthreads();

  rsl += __shfl_xor(rsl, 32, 64);
  if (hb == 0) RsD[wave][l31] = rsl;
  float* Oc = (float*)&Ks[0][0];
  if (kh == 1) {
#pragma unroll
    for (int ht = 0; ht < 4; ht++)
#pragma unroll
      for (int r = 0; r < 16; r++) {
        const int hdp = (r & 3) + 8 * (r >> 2) + 4 * hb;
        Oc[(ht * 32 + hdp) * 64 + rh * 32 + l31] = accT[ht][r];
      }
  }
  __syncthreads();
  if (kh == 0) {
    const float rinv = 1.f / (RsD[wave][l31] + RsD[wave + 2][l31]);
    const long orow = (long)(b * Sc + q0 + rh * 32 + l31);
#pragma unroll
    for (int ht = 0; ht < 4; ht++)
#pragma unroll
      for (int g2 = 0; g2 < 4; g2++) {
        bf16x4 ov;
#pragma unroll
        for (int r0 = 0; r0 < 4; r0++) {
          const int hdp = r0 + 8 * g2 + 4 * hb;
          ov[r0] = (bf16_t)((accT[ht][g2 * 4 + r0] +
                             Oc[(ht * 32 + hdp) * 64 + rh * 32 + l31]) * rinv);
        }
        *(bf16x4*)(ctx + orow * Dc + h * HDc + ht * 32 + 8 * g2 + 4 * hb) = ov;
      }
  }
}

// ---------------- workspace layout (bytes) ----------------
constexpr size_t SQB_OFF = 0;                      // bf16 8192x512: squeeze out, later ctx
constexpr size_t SEB_OFF = 8388608;                // bf16 8192x512: se
constexpr size_t Q_OFF = 16777216;                 // bf16 8192x512 (Xb aliases)
constexpr size_t K_OFF = 25165824;                 // bf16 tiled 8 MB
constexpr size_t V_OFF = 33554432;                 // bf16 tiled 8 MB
constexpr size_t XB_OFF = Q_OFF;                   // dead before q written
constexpr size_t H_OFF = K_OFF;                    // dead before k/v written
constexpr size_t QBG_OFF = 41943040;               // bf16 8192x16 = 256 KB
constexpr size_t KBG_OFF = QBG_OFF + 262144;       // bf16 128 tiles x 1024 = 256 KB
constexpr size_t WTE_OFF = KBG_OFF + 262144;       // bf16 1024x512 (1 MB)
constexpr size_t WTS_OFF = WTE_OFF + 1048576;      // bf16 512x1024 (1 MB)
constexpr size_t WTQKV_OFF = WTS_OFF + 1048576;    // bf16 1536x512 (1.5 MB)
// end = 46,137,344 bytes

extern "C" void kernel_launch(void* const* d_in, const int* in_sizes, int n_in,
                              void* d_out, int out_size, void* d_ws, size_t ws_size,
                              hipStream_t stream) {
  const float* X = (const float*)d_in[0];
  const float* pos = (const float*)d_in[1];
  const float* W_expand = (const float*)d_in[2];
  const float* b_expand = (const float*)d_in[3];
  const float* W_squeeze = (const float*)d_in[4];
  const float* b_squeeze = (const float*)d_in[5];
  const float* gamma = (const float*)d_in[6];
  const float* beta = (const float*)d_in[7];
  const float* Wq = (const float*)d_in[8];
  const float* bq = (const float*)d_in[9];
  const float* Wk = (const float*)d_in[10];
  const float* bk = (const float*)d_in[11];
  const float* Wv = (const float*)d_in[12];
  const float* bv = (const float*)d_in[13];
  const float* alphap = (const float*)d_in[14];

  char* ws = (char*)d_ws;
  bf16_t* sqb = (bf16_t*)(ws + SQB_OFF);
  bf16_t* ctxb = (bf16_t*)(ws + SQB_OFF);  // reuses sqb (sq dead after LN1)
  bf16_t* seb = (bf16_t*)(ws + SEB_OFF);
  bf16_t* qbg = (bf16_t*)(ws + QBG_OFF);
  bf16_t* kbg = (bf16_t*)(ws + KBG_OFF);
  bf16_t* qb = (bf16_t*)(ws + Q_OFF);
  bf16_t* kb = (bf16_t*)(ws + K_OFF);
  bf16_t* vb = (bf16_t*)(ws + V_OFF);
  bf16_t* xbb = (bf16_t*)(ws + XB_OFF);
  bf16_t* hb = (bf16_t*)(ws + H_OFF);
  bf16_t* wtE = (bf16_t*)(ws + WTE_OFF);
  bf16_t* wtS = (bf16_t*)(ws + WTS_OFF);
  bf16_t* wtQKV = (bf16_t*)(ws + WTQKV_OFF);

  // prep: X cast + bias frags + weight transposes (one launch)
  prep_k<<<3872, 256, 0, stream>>>(X, xbb, pos, alphap, qbg, kbg,
                                   W_expand, wtE, W_squeeze, wtS, Wq, Wk, Wv, wtQKV);
  // h = relu(X @ We + be)            [8192,1024] bf16
  gemm128_k<0, 128, 8><<<512, 256, 0, stream>>>(
      xbb, wtE, b_expand, nullptr, nullptr, hb, nullptr, nullptr, 1024, 512);
  // sq = h @ Ws + bs                 [8192,512] bf16
  gemm128_k<1, 64, 8><<<512, 256, 0, stream>>>(
      hb, wtS, b_squeeze, nullptr, nullptr, sqb, nullptr, nullptr, 512, 1024);
  // se = LN(X + sq)  -> bf16
  ln_k<1, 0><<<Mrows / 4, 256, 0, stream>>>(X, sqb, gamma, beta, seb);
  // q,k,v = se @ [Wq|Wk|Wv] + b
  gemm128_k<2, 128, 12><<<768, 256, 0, stream>>>(
      seb, wtQKV, bq, bk, bv, qb, kb, vb, 1536, 512);
  // ctx = attention (bias folded into MFMA)
  attn_k<<<512, 256, 0, stream>>>(qb, kb, vb, qbg, kbg, ctxb);
  // out = LN(se + ctx) -> fp32
  ln_k<0, 1><<<Mrows / 4, 256, 0, stream>>>(seb, ctxb, gamma, beta, (float*)d_out);

  (void)in_sizes; (void)n_in; (void)out_size; (void)ws_size;
}